// Round 1
// baseline (496.888 us; speedup 1.0000x reference)
//
#include <hip/hip_runtime.h>
#include <math.h>

// ---------------------------------------------------------------------------
// ShrdMHAttention: z = (sum_h softmax_causal(rope(xQ) rope(xK)^T) (xV) O_h) * scale
// SEQ=2048, D_MODEL=2048, NH=16, DQK=DV=128.
//
// Precision plan: scores have sigma~2048 with softmax temp 1 -> near-argmax.
// q/k projections and QK^T use 2-term fp16 split (3 MFMAs: hh+hl+lh) so score
// error ~1e-3 (no argmax flips). v-proj / PV / out-proj are single fp16.
// ---------------------------------------------------------------------------

typedef _Float16 half_t;
typedef __attribute__((ext_vector_type(8))) _Float16 half8;
typedef __attribute__((ext_vector_type(4))) float f32x4;

#define SEQ   2048
#define DM    2048
#define NHEAD 16
#define DHEAD 128

__device__ __forceinline__ f32x4 mfma16(half8 a, half8 b, f32x4 c) {
  return __builtin_amdgcn_mfma_f32_16x16x32_f16(a, b, c, 0, 0, 0);
}

// async global->LDS, 16B per lane; LDS dest is wave-uniform base + lane*16
__device__ __forceinline__ void gll16(const half_t* g, half_t* l) {
  __builtin_amdgcn_global_load_lds(
      (const __attribute__((address_space(1))) unsigned int*)g,
      (__attribute__((address_space(3))) unsigned int*)l, 16, 0, 0);
}

// ---------------------------------------------------------------------------
// x (fp32) -> hi/lo fp16 split, vectorized x4
__global__ __launch_bounds__(256)
void k_split4(const float* __restrict__ in, half_t* __restrict__ hi,
              half_t* __restrict__ lo, int n4) {
  int i = blockIdx.x * 256 + threadIdx.x;
  if (i >= n4) return;
  float4 v = ((const float4*)in)[i];
  union { half_t h[4]; uint2 u; } H, L;
  H.h[0] = (half_t)v.x; H.h[1] = (half_t)v.y;
  H.h[2] = (half_t)v.z; H.h[3] = (half_t)v.w;
  L.h[0] = (half_t)(v.x - (float)H.h[0]);
  L.h[1] = (half_t)(v.y - (float)H.h[1]);
  L.h[2] = (half_t)(v.z - (float)H.h[2]);
  L.h[3] = (half_t)(v.w - (float)H.h[3]);
  *(uint2*)&hi[(size_t)i * 4] = H.u;
  *(uint2*)&lo[(size_t)i * 4] = L.u;
}

// ---------------------------------------------------------------------------
// fp32 [z][R][C] -> fp16 transposed [z][C][R], hi (+ optional lo split)
__global__ __launch_bounds__(256)
void k_transpose(const float* __restrict__ in, half_t* __restrict__ hi,
                 half_t* __restrict__ lo, int R, int C) {
  __shared__ float tile[32][33];
  size_t bo = (size_t)blockIdx.z * R * C;
  int c0 = blockIdx.x * 32, r0 = blockIdx.y * 32;
  int tx = threadIdx.x & 31, ty = threadIdx.x >> 5;   // 32 x 8
#pragma unroll
  for (int i = 0; i < 32; i += 8)
    tile[ty + i][tx] = in[bo + (size_t)(r0 + ty + i) * C + c0 + tx];
  __syncthreads();
#pragma unroll
  for (int i = 0; i < 32; i += 8) {
    float v = tile[tx][ty + i];            // = in[r0+tx][c0+ty+i]
    half_t h = (half_t)v;
    size_t oidx = bo + (size_t)(c0 + ty + i) * R + r0 + tx;
    hi[oidx] = h;
    if (lo) lo[oidx] = (half_t)(v - (float)h);
  }
}

// ---------------------------------------------------------------------------
// Split-fp16 projection: Craw[y][s][e] = sum_d X[s][d] * W_y[d][e], y = which*16+h
// A = Xh/Xl [2048][2048]; B from WT hi/lo [y][128 e][2048 d] (k-contiguous).
// 3-term split: Ah*Bh + Ah*Bl + Al*Bh.  BM=BN=128, BK=32, 4 waves (2x2).
__global__ __launch_bounds__(256)
void k_proj(const half_t* __restrict__ Xh, const half_t* __restrict__ Xl,
            const half_t* __restrict__ WTh, const half_t* __restrict__ WTl,
            float* __restrict__ Craw) {
  __shared__ __align__(16) half_t sAh[128 * 32], sAl[128 * 32];
  __shared__ __align__(16) half_t sBh[128 * 32], sBl[128 * 32];
  int y = blockIdx.y;
  int m0 = blockIdx.x * 128;
  const half_t* wth = WTh + (size_t)y * 128 * DM;
  const half_t* wtl = WTl + (size_t)y * 128 * DM;
  int lane = threadIdx.x & 63, wave = threadIdx.x >> 6;
  int l15 = lane & 15, quad = lane >> 4;
  int wm = wave >> 1, wn = wave & 1;
  int srow = lane >> 2, scol = (lane & 3) * 8;  // 4 lanes/row of 32 halfs

  f32x4 acc[4][4];
#pragma unroll
  for (int a = 0; a < 4; ++a)
#pragma unroll
    for (int b = 0; b < 4; ++b) acc[a][b] = (f32x4)0.0f;

  for (int kt = 0; kt < DM / 32; ++kt) {
    int k0 = kt * 32;
#pragma unroll
    for (int i = 0; i < 2; ++i) {
      int c = wave * 2 + i;
      size_t ro = (size_t)(c * 16 + srow) * DM + k0 + scol;
      gll16(Xh + (size_t)m0 * DM + ro, sAh + c * 512);
      gll16(Xl + (size_t)m0 * DM + ro, sAl + c * 512);
      gll16(wth + ro, sBh + c * 512);
      gll16(wtl + ro, sBl + c * 512);
    }
    __syncthreads();
    half8 ah[4], al[4], bh[4], bl[4];
#pragma unroll
    for (int t = 0; t < 4; ++t) {
      int ao = (wm * 64 + t * 16 + l15) * 32 + quad * 8;
      int bo = (wn * 64 + t * 16 + l15) * 32 + quad * 8;
      ah[t] = *(const half8*)&sAh[ao];
      al[t] = *(const half8*)&sAl[ao];
      bh[t] = *(const half8*)&sBh[bo];
      bl[t] = *(const half8*)&sBl[bo];
    }
#pragma unroll
    for (int im = 0; im < 4; ++im)
#pragma unroll
      for (int in = 0; in < 4; ++in) {
        acc[im][in] = mfma16(ah[im], bh[in], acc[im][in]);
        acc[im][in] = mfma16(ah[im], bl[in], acc[im][in]);
        acc[im][in] = mfma16(al[im], bh[in], acc[im][in]);
      }
    __syncthreads();
  }
  float* cb = Craw + (size_t)y * SEQ * 128;
#pragma unroll
  for (int im = 0; im < 4; ++im)
#pragma unroll
    for (int in = 0; in < 4; ++in)
#pragma unroll
      for (int r = 0; r < 4; ++r) {
        int row = m0 + wm * 64 + im * 16 + quad * 4 + r;
        int col = wn * 64 + in * 16 + l15;
        cb[(size_t)row * 128 + col] = acc[im][in][r];
      }
}

// ---------------------------------------------------------------------------
// RoPE + 1/dqk^0.25 scale + hi/lo fp16 split.  Bit-exact rot: rate is exactly
// representable, rot = one fp32 multiply (matches numpy), accurate sinf/cosf.
__global__ __launch_bounds__(256)
void k_rope(const float* __restrict__ Craw, half_t* __restrict__ Rh,
            half_t* __restrict__ Rl, const float* __restrict__ thetap) {
  int which = blockIdx.z, h = blockIdx.y;
  int s = blockIdx.x * 4 + (threadIdx.x >> 6);
  int e = threadIdx.x & 63;
  float th = thetap[0];
  size_t base = ((size_t)(which * NHEAD + h) * SEQ + s) * 128;
  float x1 = Craw[base + e];
  float x2 = Craw[base + 64 + e];
  float rate = th * (-(float)e * (1.0f / 64.0f));  // exact
  float rot = (float)s * rate;                     // single fp32 mul
  float sn = sinf(rot), cs = cosf(rot);
  const float inv4 = 0.2973017787506803f;          // 128^-0.25
  float y1 = (cs * x1 - sn * x2) * inv4;
  float y2 = (sn * x1 + cs * x2) * inv4;
  half_t h1 = (half_t)y1, h2 = (half_t)y2;
  Rh[base + e] = h1;       Rl[base + e] = (half_t)(y1 - (float)h1);
  Rh[base + 64 + e] = h2;  Rl[base + 64 + e] = (half_t)(y2 - (float)h2);
}

// ---------------------------------------------------------------------------
// Single-term fp16 GEMM: C[am0+m][bn0+n] = scale * sum_k A[am0+m][k]*B[bn0+n][k]
// A,B row-major with ld=2048 (k contiguous).  Used for v-proj (half out) and
// out-proj (fp32 out).
template <int HALF_OUT>
__global__ __launch_bounds__(256)
void k_gemm1(const half_t* __restrict__ A, const half_t* __restrict__ B,
             void* __restrict__ Cv, float scale) {
  __shared__ __align__(16) half_t sA[128 * 32], sB[128 * 32];
  int am0 = blockIdx.y * 128, bn0 = blockIdx.x * 128;
  int lane = threadIdx.x & 63, wave = threadIdx.x >> 6;
  int l15 = lane & 15, quad = lane >> 4;
  int wm = wave >> 1, wn = wave & 1;
  int srow = lane >> 2, scol = (lane & 3) * 8;

  f32x4 acc[4][4];
#pragma unroll
  for (int a = 0; a < 4; ++a)
#pragma unroll
    for (int b = 0; b < 4; ++b) acc[a][b] = (f32x4)0.0f;

  for (int kt = 0; kt < DM / 32; ++kt) {
    int k0 = kt * 32;
#pragma unroll
    for (int i = 0; i < 2; ++i) {
      int c = wave * 2 + i;
      size_t ro = (size_t)(c * 16 + srow) * 2048 + k0 + scol;
      gll16(A + (size_t)am0 * 2048 + ro, sA + c * 512);
      gll16(B + (size_t)bn0 * 2048 + ro, sB + c * 512);
    }
    __syncthreads();
    half8 ah[4], bh[4];
#pragma unroll
    for (int t = 0; t < 4; ++t) {
      ah[t] = *(const half8*)&sA[(wm * 64 + t * 16 + l15) * 32 + quad * 8];
      bh[t] = *(const half8*)&sB[(wn * 64 + t * 16 + l15) * 32 + quad * 8];
    }
#pragma unroll
    for (int im = 0; im < 4; ++im)
#pragma unroll
      for (int in = 0; in < 4; ++in)
        acc[im][in] = mfma16(ah[im], bh[in], acc[im][in]);
    __syncthreads();
  }
#pragma unroll
  for (int im = 0; im < 4; ++im)
#pragma unroll
    for (int in = 0; in < 4; ++in)
#pragma unroll
      for (int r = 0; r < 4; ++r) {
        int row = am0 + wm * 64 + im * 16 + quad * 4 + r;
        int col = bn0 + wn * 64 + in * 16 + l15;
        if (HALF_OUT)
          ((half_t*)Cv)[(size_t)row * 2048 + col] = (half_t)(acc[im][in][r] * scale);
        else
          ((float*)Cv)[(size_t)row * 2048 + col] = acc[im][in][r] * scale;
      }
}

// ---------------------------------------------------------------------------
// Flash attention, causal.  BM=BN=64, 4 waves, wave owns 16 q-rows (all stats
// wave-local).  Split-fp16 QK^T (3 MFMAs), plain fp16 PV.  Q frags persistent
// in registers.  Grid 512 = (qtile reversed: longest first) x 16 heads.
__global__ __launch_bounds__(256)
void k_flash(const half_t* __restrict__ Rh, const half_t* __restrict__ Rl,
             const half_t* __restrict__ VST, half_t* __restrict__ Ybig) {
  int idx = blockIdx.x;
  int h = idx & 15;
  int qt = 31 - (idx >> 4);           // longest blocks launched first
  int lane = threadIdx.x & 63, wave = threadIdx.x >> 6;
  int l15 = lane & 15, quad = lane >> 4;

  const half_t* RQh = Rh + (size_t)h * SEQ * 128;
  const half_t* RQl = Rl + (size_t)h * SEQ * 128;
  const half_t* RKh = Rh + (size_t)(NHEAD + h) * SEQ * 128;
  const half_t* RKl = Rl + (size_t)(NHEAD + h) * SEQ * 128;
  const half_t* Vt  = VST + (size_t)h * 128 * SEQ;   // [v][t]

  __shared__ __align__(16) half_t smem[28672];  // 56 KB
  half_t* sKh = smem;            // [64 t][128 e]
  half_t* sKl = smem + 8192;
  half_t* sVt = smem + 16384;    // [128 v][64 t]
  half_t* sP  = smem + 24576;    // [64 s][64 t]

  int q0 = qt * 64;

  // stage Q tile (64x128 hi+lo) into smem[0..16384), then lift frags to regs
#pragma unroll
  for (int i = 0; i < 4; ++i) {
    int c = wave * 4 + i;
    size_t ro = (size_t)(q0 + c * 4 + quad) * 128 + l15 * 8;
    gll16(RQh + ro, smem + c * 512);
    gll16(RQl + ro, smem + 8192 + c * 512);
  }
  __syncthreads();
  half8 qh[4], ql[4];
#pragma unroll
  for (int kk = 0; kk < 4; ++kk) {
    int o = (wave * 16 + l15) * 128 + kk * 32 + quad * 8;
    qh[kk] = *(const half8*)&smem[o];
    ql[kk] = *(const half8*)&smem[8192 + o];
  }
  __syncthreads();  // before K staging overwrites Q

  float m_st[4], l_st[4];
  f32x4 oacc[8];
#pragma unroll
  for (int r = 0; r < 4; ++r) { m_st[r] = -INFINITY; l_st[r] = 0.0f; }
#pragma unroll
  for (int iv = 0; iv < 8; ++iv) oacc[iv] = (f32x4)0.0f;

  int nkb = qt + 1;
  for (int kb = 0; kb < nkb; ++kb) {
    int t0 = kb * 64;
#pragma unroll
    for (int i = 0; i < 4; ++i) {
      int c = wave * 4 + i;
      size_t kro = (size_t)(t0 + c * 4 + quad) * 128 + l15 * 8;
      gll16(RKh + kro, sKh + c * 512);
      gll16(RKl + kro, sKl + c * 512);
      gll16(Vt + (size_t)(c * 8 + (lane >> 3)) * SEQ + t0 + (lane & 7) * 8,
            sVt + c * 512);
    }
    __syncthreads();

    // S = Q K^T (split), rows wave*16..+15, cols 0..63
    f32x4 sacc[4];
#pragma unroll
    for (int in = 0; in < 4; ++in) sacc[in] = (f32x4)0.0f;
#pragma unroll
    for (int kk = 0; kk < 4; ++kk) {
#pragma unroll
      for (int in = 0; in < 4; ++in) {
        int bo = (in * 16 + l15) * 128 + kk * 32 + quad * 8;
        half8 bh = *(const half8*)&sKh[bo];
        half8 bl = *(const half8*)&sKl[bo];
        sacc[in] = mfma16(qh[kk], bh, sacc[in]);
        sacc[in] = mfma16(qh[kk], bl, sacc[in]);
        sacc[in] = mfma16(ql[kk], bh, sacc[in]);
      }
    }
    if (kb == qt) {  // diagonal block: mask t > s
#pragma unroll
      for (int in = 0; in < 4; ++in)
#pragma unroll
        for (int r = 0; r < 4; ++r) {
          int srow = wave * 16 + quad * 4 + r;
          int tcol = in * 16 + l15;
          if (tcol > srow) sacc[in][r] = -1e30f;
        }
    }
    // online softmax (row stats wave-local; 16-lane xor reduction)
    float alpha[4];
#pragma unroll
    for (int r = 0; r < 4; ++r) {
      float mx = fmaxf(fmaxf(sacc[0][r], sacc[1][r]),
                       fmaxf(sacc[2][r], sacc[3][r]));
#pragma unroll
      for (int off = 1; off < 16; off <<= 1)
        mx = fmaxf(mx, __shfl_xor(mx, off, 64));
      float mnew = fmaxf(m_st[r], mx);
      alpha[r] = __expf(m_st[r] - mnew);
      float sum = 0.0f;
#pragma unroll
      for (int in = 0; in < 4; ++in) {
        float p = __expf(sacc[in][r] - mnew);
        sacc[in][r] = p;
        sum += p;
      }
#pragma unroll
      for (int off = 1; off < 16; off <<= 1) sum += __shfl_xor(sum, off, 64);
      l_st[r] = l_st[r] * alpha[r] + sum;
      m_st[r] = mnew;
    }
    // write P (wave-local rows) + rescale O
#pragma unroll
    for (int in = 0; in < 4; ++in)
#pragma unroll
      for (int r = 0; r < 4; ++r)
        sP[(wave * 16 + quad * 4 + r) * 64 + in * 16 + l15] =
            (half_t)sacc[in][r];
#pragma unroll
    for (int iv = 0; iv < 8; ++iv)
#pragma unroll
      for (int r = 0; r < 4; ++r) oacc[iv][r] *= alpha[r];

    // O += P @ V   (A=P wave-local rows, B=Vt [v][t])
#pragma unroll
    for (int kk2 = 0; kk2 < 2; ++kk2) {
      half8 pa = *(const half8*)&sP[(wave * 16 + l15) * 64 + kk2 * 32 + quad * 8];
#pragma unroll
      for (int iv = 0; iv < 8; ++iv) {
        half8 vb =
            *(const half8*)&sVt[(iv * 16 + l15) * 64 + kk2 * 32 + quad * 8];
        oacc[iv] = mfma16(pa, vb, oacc[iv]);
      }
    }
    __syncthreads();  // protect sK/sV/sP before next staging
  }
  // epilogue: O / l -> Ybig[s][h*128+v]
  float invl[4];
#pragma unroll
  for (int r = 0; r < 4; ++r) invl[r] = 1.0f / l_st[r];
#pragma unroll
  for (int iv = 0; iv < 8; ++iv)
#pragma unroll
    for (int r = 0; r < 4; ++r) {
      int row = q0 + wave * 16 + quad * 4 + r;
      int col = h * 128 + iv * 16 + l15;
      Ybig[(size_t)row * 2048 + col] = (half_t)(oacc[iv][r] * invl[r]);
    }
}

// ---------------------------------------------------------------------------
extern "C" void kernel_launch(void* const* d_in, const int* in_sizes, int n_in,
                              void* d_out, int out_size, void* d_ws,
                              size_t ws_size, hipStream_t stream) {
  const float* x = (const float*)d_in[0];
  const float* q = (const float*)d_in[1];
  const float* k = (const float*)d_in[2];
  const float* v = (const float*)d_in[3];
  const float* o = (const float*)d_in[4];
  const float* theta = (const float*)d_in[5];
  float* out = (float*)d_out;

  char* ws = (char*)d_ws;
  const size_t HB = (size_t)2048 * 2048 * 2;  // 8 MiB
  half_t* Xh  = (half_t*)(ws);
  half_t* Xl  = (half_t*)(ws + HB);
  half_t* WTh = (half_t*)(ws + 2 * HB);  // [2][16][128][2048]; reused as Rh
  half_t* WTl = (half_t*)(ws + 4 * HB);  // reused as Rl
  half_t* VhT = (half_t*)(ws + 6 * HB);  // [16][128][2048]
  half_t* OT  = (half_t*)(ws + 7 * HB);  // [2048 d][2048 hv]
  float*  Craw = (float*)(ws + 8 * HB);  // [2][16][2048][128] fp32 (4 HB)
  half_t* Rh = WTh;                      // rope output overlays weights
  half_t* Rl = WTl;
  half_t* VST  = (half_t*)(ws + 8 * HB); // overlays Craw (dead after rope)
  half_t* Ybig = (half_t*)(ws + 9 * HB);

  // 1. split x -> fp16 hi/lo
  k_split4<<<4096, 256, 0, stream>>>(x, Xh, Xl, (2048 * 2048) / 4);
  // 2. weight transposes (k-contiguous B layouts for MFMA)
  k_transpose<<<dim3(4, 64, 16), 256, 0, stream>>>(q, WTh, WTl, 2048, 128);
  k_transpose<<<dim3(4, 64, 16), 256, 0, stream>>>(
      k, WTh + (size_t)16 * 128 * 2048, WTl + (size_t)16 * 128 * 2048, 2048, 128);
  k_transpose<<<dim3(4, 64, 16), 256, 0, stream>>>(v, VhT, nullptr, 2048, 128);
  k_transpose<<<dim3(64, 64, 1), 256, 0, stream>>>(o, OT, nullptr, 2048, 2048);
  // 3. q/k projections, split fp16 (3-term)
  k_proj<<<dim3(16, 32), 256, 0, stream>>>(Xh, Xl, WTh, WTl, Craw);
  // 4. rope + scale + re-split (Craw consumed; frees region for VST/Ybig)
  k_rope<<<dim3(512, 16, 2), 256, 0, stream>>>(Craw, Rh, Rl, theta);
  // 5. v projection -> VS^T [h][v][t] fp16 (C' = V^T X^T trick: no transpose)
  k_gemm1<1><<<dim3(16, 16), 256, 0, stream>>>(VhT, Xh, VST, 1.0f);
  // 6. flash attention -> Ybig [s][h*128+v] fp16
  k_flash<<<512, 256, 0, stream>>>(Rh, Rl, VST, Ybig);
  // 7. out projection: z = Ybig @ O * (1/2048) -> fp32
  k_gemm1<0><<<dim3(16, 16), 256, 0, stream>>>(Ybig, OT, out, 1.0f / 2048.0f);
}

// Round 2
// 471.409 us; speedup vs baseline: 1.0540x; 1.0540x over previous
//
#include <hip/hip_runtime.h>
#include <math.h>

// ---------------------------------------------------------------------------
// ShrdMHAttention: z = (sum_h softmax_causal(rope(xQ) rope(xK)^T) (xV) O_h) * scale
// SEQ=2048, D_MODEL=2048, NH=16, DQK=DV=128.
//
// Precision: q/k proj and QK^T use 2-term fp16 split (hh+hl+lh); v/PV/out are
// single fp16.  R1 measured absmax 0.031 vs 0.102 threshold.
//
// R2: XOR chunk-swizzled LDS everywhere (R1 flash had 16-way bank conflicts:
// row strides 256B/128B make bank independent of l15; SQ_LDS_BANK_CONFLICT
// 3.9e7).  Flash rebuilt with BM=128 (wave owns 32 rows -> K-tile LDS reads
// amortized 2x), Q frags direct from global, wave-private P roundtrip.
// ---------------------------------------------------------------------------

typedef _Float16 half_t;
typedef __attribute__((ext_vector_type(8))) _Float16 half8;
typedef __attribute__((ext_vector_type(4))) float f32x4;

#define SEQ   2048
#define DM    2048
#define NHEAD 16

__device__ __forceinline__ f32x4 mfma16(half8 a, half8 b, f32x4 c) {
  return __builtin_amdgcn_mfma_f32_16x16x32_f16(a, b, c, 0, 0, 0);
}

__device__ __forceinline__ void gll16(const half_t* g, half_t* l) {
  __builtin_amdgcn_global_load_lds(
      (const __attribute__((address_space(1))) unsigned int*)g,
      (__attribute__((address_space(3))) unsigned int*)l, 16, 0, 0);
}

// ---------------------------------------------------------------------------
__global__ __launch_bounds__(256)
void k_split4(const float* __restrict__ in, half_t* __restrict__ hi,
              half_t* __restrict__ lo, int n4) {
  int i = blockIdx.x * 256 + threadIdx.x;
  if (i >= n4) return;
  float4 v = ((const float4*)in)[i];
  union { half_t h[4]; uint2 u; } H, L;
  H.h[0] = (half_t)v.x; H.h[1] = (half_t)v.y;
  H.h[2] = (half_t)v.z; H.h[3] = (half_t)v.w;
  L.h[0] = (half_t)(v.x - (float)H.h[0]);
  L.h[1] = (half_t)(v.y - (float)H.h[1]);
  L.h[2] = (half_t)(v.z - (float)H.h[2]);
  L.h[3] = (half_t)(v.w - (float)H.h[3]);
  *(uint2*)&hi[(size_t)i * 4] = H.u;
  *(uint2*)&lo[(size_t)i * 4] = L.u;
}

// ---------------------------------------------------------------------------
__global__ __launch_bounds__(256)
void k_transpose(const float* __restrict__ in, half_t* __restrict__ hi,
                 half_t* __restrict__ lo, int R, int C) {
  __shared__ float tile[32][33];
  size_t bo = (size_t)blockIdx.z * R * C;
  int c0 = blockIdx.x * 32, r0 = blockIdx.y * 32;
  int tx = threadIdx.x & 31, ty = threadIdx.x >> 5;
#pragma unroll
  for (int i = 0; i < 32; i += 8)
    tile[ty + i][tx] = in[bo + (size_t)(r0 + ty + i) * C + c0 + tx];
  __syncthreads();
#pragma unroll
  for (int i = 0; i < 32; i += 8) {
    float v = tile[tx][ty + i];
    half_t h = (half_t)v;
    size_t oidx = bo + (size_t)(c0 + ty + i) * R + r0 + tx;
    hi[oidx] = h;
    if (lo) lo[oidx] = (half_t)(v - (float)h);
  }
}

// ---------------------------------------------------------------------------
// GEMM LDS tiles: rows of 32 halfs = 4 chunks of 16B.  Swizzle: physical
// chunk = logical ^ ((row>>1)&3)  ->  fragment-read start banks 2-way (free).
// Staging lane l: row = l>>2, phys chunk = l&3, so logical = (l&3)^((l>>3)&3).
__device__ __forceinline__ int gemm_scol(int lane) {
  return (((lane & 3) ^ ((lane >> 3) & 3)) * 8);
}
__device__ __forceinline__ int gemm_fo(int row, int quad, int l15) {
  return row * 32 + ((quad ^ ((l15 >> 1) & 3)) * 8);
}

// Split-fp16 projection (3-term).  BM=BN=128, BK=32, 4 waves (2x2).
__global__ __launch_bounds__(256)
void k_proj(const half_t* __restrict__ Xh, const half_t* __restrict__ Xl,
            const half_t* __restrict__ WTh, const half_t* __restrict__ WTl,
            float* __restrict__ Craw) {
  __shared__ __align__(16) half_t sAh[128 * 32], sAl[128 * 32];
  __shared__ __align__(16) half_t sBh[128 * 32], sBl[128 * 32];
  int y = blockIdx.y;
  int m0 = blockIdx.x * 128;
  const half_t* wth = WTh + (size_t)y * 128 * DM;
  const half_t* wtl = WTl + (size_t)y * 128 * DM;
  int lane = threadIdx.x & 63, wave = threadIdx.x >> 6;
  int l15 = lane & 15, quad = lane >> 4;
  int wm = wave >> 1, wn = wave & 1;
  int srow = lane >> 2, scol = gemm_scol(lane);

  f32x4 acc[4][4];
#pragma unroll
  for (int a = 0; a < 4; ++a)
#pragma unroll
    for (int b = 0; b < 4; ++b) acc[a][b] = (f32x4)0.0f;

  for (int kt = 0; kt < DM / 32; ++kt) {
    int k0 = kt * 32;
#pragma unroll
    for (int i = 0; i < 2; ++i) {
      int c = wave * 2 + i;
      size_t ro = (size_t)(c * 16 + srow) * DM + k0 + scol;
      gll16(Xh + (size_t)m0 * DM + ro, sAh + c * 512);
      gll16(Xl + (size_t)m0 * DM + ro, sAl + c * 512);
      gll16(wth + ro, sBh + c * 512);
      gll16(wtl + ro, sBl + c * 512);
    }
    __syncthreads();
    half8 ah[4], al[4], bh[4], bl[4];
#pragma unroll
    for (int t = 0; t < 4; ++t) {
      int ao = gemm_fo(wm * 64 + t * 16 + l15, quad, l15);
      int bo = gemm_fo(wn * 64 + t * 16 + l15, quad, l15);
      ah[t] = *(const half8*)&sAh[ao];
      al[t] = *(const half8*)&sAl[ao];
      bh[t] = *(const half8*)&sBh[bo];
      bl[t] = *(const half8*)&sBl[bo];
    }
#pragma unroll
    for (int im = 0; im < 4; ++im)
#pragma unroll
      for (int in = 0; in < 4; ++in) {
        acc[im][in] = mfma16(ah[im], bh[in], acc[im][in]);
        acc[im][in] = mfma16(ah[im], bl[in], acc[im][in]);
        acc[im][in] = mfma16(al[im], bh[in], acc[im][in]);
      }
    __syncthreads();
  }
  float* cb = Craw + (size_t)y * SEQ * 128;
#pragma unroll
  for (int im = 0; im < 4; ++im)
#pragma unroll
    for (int in = 0; in < 4; ++in)
#pragma unroll
      for (int r = 0; r < 4; ++r) {
        int row = m0 + wm * 64 + im * 16 + quad * 4 + r;
        int col = wn * 64 + in * 16 + l15;
        cb[(size_t)row * 128 + col] = acc[im][in][r];
      }
}

// ---------------------------------------------------------------------------
__global__ __launch_bounds__(256)
void k_rope(const float* __restrict__ Craw, half_t* __restrict__ Rh,
            half_t* __restrict__ Rl, const float* __restrict__ thetap) {
  int which = blockIdx.z, h = blockIdx.y;
  int s = blockIdx.x * 4 + (threadIdx.x >> 6);
  int e = threadIdx.x & 63;
  float th = thetap[0];
  size_t base = ((size_t)(which * NHEAD + h) * SEQ + s) * 128;
  float x1 = Craw[base + e];
  float x2 = Craw[base + 64 + e];
  float rate = th * (-(float)e * (1.0f / 64.0f));
  float rot = (float)s * rate;
  float sn = sinf(rot), cs = cosf(rot);
  const float inv4 = 0.2973017787506803f;  // 128^-0.25
  float y1 = (cs * x1 - sn * x2) * inv4;
  float y2 = (sn * x1 + cs * x2) * inv4;
  half_t h1 = (half_t)y1, h2 = (half_t)y2;
  Rh[base + e] = h1;       Rl[base + e] = (half_t)(y1 - (float)h1);
  Rh[base + 64 + e] = h2;  Rl[base + 64 + e] = (half_t)(y2 - (float)h2);
}

// ---------------------------------------------------------------------------
template <int HALF_OUT>
__global__ __launch_bounds__(256)
void k_gemm1(const half_t* __restrict__ A, const half_t* __restrict__ B,
             void* __restrict__ Cv, float scale) {
  __shared__ __align__(16) half_t sA[128 * 32], sB[128 * 32];
  int am0 = blockIdx.y * 128, bn0 = blockIdx.x * 128;
  int lane = threadIdx.x & 63, wave = threadIdx.x >> 6;
  int l15 = lane & 15, quad = lane >> 4;
  int wm = wave >> 1, wn = wave & 1;
  int srow = lane >> 2, scol = gemm_scol(lane);

  f32x4 acc[4][4];
#pragma unroll
  for (int a = 0; a < 4; ++a)
#pragma unroll
    for (int b = 0; b < 4; ++b) acc[a][b] = (f32x4)0.0f;

  for (int kt = 0; kt < DM / 32; ++kt) {
    int k0 = kt * 32;
#pragma unroll
    for (int i = 0; i < 2; ++i) {
      int c = wave * 2 + i;
      size_t ro = (size_t)(c * 16 + srow) * 2048 + k0 + scol;
      gll16(A + (size_t)am0 * 2048 + ro, sA + c * 512);
      gll16(B + (size_t)bn0 * 2048 + ro, sB + c * 512);
    }
    __syncthreads();
    half8 ah[4], bh[4];
#pragma unroll
    for (int t = 0; t < 4; ++t) {
      ah[t] = *(const half8*)&sA[gemm_fo(wm * 64 + t * 16 + l15, quad, l15)];
      bh[t] = *(const half8*)&sB[gemm_fo(wn * 64 + t * 16 + l15, quad, l15)];
    }
#pragma unroll
    for (int im = 0; im < 4; ++im)
#pragma unroll
      for (int in = 0; in < 4; ++in)
        acc[im][in] = mfma16(ah[im], bh[in], acc[im][in]);
    __syncthreads();
  }
#pragma unroll
  for (int im = 0; im < 4; ++im)
#pragma unroll
    for (int in = 0; in < 4; ++in)
#pragma unroll
      for (int r = 0; r < 4; ++r) {
        int row = am0 + wm * 64 + im * 16 + quad * 4 + r;
        int col = bn0 + wn * 64 + in * 16 + l15;
        if (HALF_OUT)
          ((half_t*)Cv)[(size_t)row * 2048 + col] = (half_t)(acc[im][in][r] * scale);
        else
          ((float*)Cv)[(size_t)row * 2048 + col] = acc[im][in][r] * scale;
      }
}

// ---------------------------------------------------------------------------
// Flash attention, causal.  BM=128 (wave owns 32 q-rows), BN=64.
// Grid 256 = 16 qtiles (longest first) x 16 heads -> 1 block/CU.
// K tile rows = 256B = 16 chunks, swizzle key row&15.
// V tile rows = 128B = 8 chunks, swizzle key row&7.
// P: wave-private LDS roundtrip (no barrier), stride 72 halfs.
__global__ __launch_bounds__(256, 1)
void k_flash(const half_t* __restrict__ Rh, const half_t* __restrict__ Rl,
             const half_t* __restrict__ VST, half_t* __restrict__ Ybig) {
  int idx = blockIdx.x;
  int h = idx & 15;
  int qt = 15 - (idx >> 4);
  int lane = threadIdx.x & 63, wave = threadIdx.x >> 6;
  int l15 = lane & 15, quad = lane >> 4;

  const half_t* RQh = Rh + (size_t)h * SEQ * 128;
  const half_t* RQl = Rl + (size_t)h * SEQ * 128;
  const half_t* RKh = Rh + (size_t)(NHEAD + h) * SEQ * 128;
  const half_t* RKl = Rl + (size_t)(NHEAD + h) * SEQ * 128;
  const half_t* Vt  = VST + (size_t)h * 128 * SEQ;  // [v][t]

  __shared__ __align__(16) half_t sKh[64 * 128];
  __shared__ __align__(16) half_t sKl[64 * 128];
  __shared__ __align__(16) half_t sVt[128 * 64];
  __shared__ __align__(16) half_t sP[128 * 72];

  int q0 = qt * 128;

  // Q fragments direct from global (one-time, L2-resident)
  half8 qh[2][4], ql[2][4];
#pragma unroll
  for (int im = 0; im < 2; ++im)
#pragma unroll
    for (int kk = 0; kk < 4; ++kk) {
      size_t ad =
          (size_t)(q0 + wave * 32 + im * 16 + l15) * 128 + kk * 32 + quad * 8;
      qh[im][kk] = *(const half8*)&RQh[ad];
      ql[im][kk] = *(const half8*)&RQl[ad];
    }

  float m_st[2][4], l_st[2][4];
  f32x4 oacc[2][8];
#pragma unroll
  for (int im = 0; im < 2; ++im)
#pragma unroll
    for (int r = 0; r < 4; ++r) { m_st[im][r] = -INFINITY; l_st[im][r] = 0.0f; }
#pragma unroll
  for (int im = 0; im < 2; ++im)
#pragma unroll
    for (int iv = 0; iv < 8; ++iv) oacc[im][iv] = (f32x4)0.0f;

  int nkb = 2 * qt + 2;
  for (int kb = 0; kb < nkb; ++kb) {
    int t0 = kb * 64;
    // ---- stage K (hi+lo) and V, swizzled ----
#pragma unroll
    for (int i = 0; i < 4; ++i) {
      int c = wave * 4 + i;
      int rk = c * 4 + (lane >> 4);                 // K row 0..63
      int ck = (lane & 15) ^ (rk & 15);             // logical chunk
      gll16(RKh + (size_t)(t0 + rk) * 128 + ck * 8, sKh + c * 512);
      gll16(RKl + (size_t)(t0 + rk) * 128 + ck * 8, sKl + c * 512);
      int rv = c * 8 + (lane >> 3);                 // V row 0..127
      int cv = (lane & 7) ^ (rv & 7);
      gll16(Vt + (size_t)rv * SEQ + t0 + cv * 8, sVt + c * 512);
    }
    __syncthreads();

    // waves whose rows are entirely < t0 are fully masked on this kb
    bool wave_live = (q0 + wave * 32 + 31 >= t0);
    if (wave_live) {
#pragma unroll
      for (int im = 0; im < 2; ++im) {
        f32x4 sacc[4];
#pragma unroll
        for (int in = 0; in < 4; ++in) sacc[in] = (f32x4)0.0f;
#pragma unroll
        for (int kk = 0; kk < 4; ++kk)
#pragma unroll
          for (int in = 0; in < 4; ++in) {
            int bo = (in * 16 + l15) * 128 + (((kk * 4 + quad) ^ l15) * 8);
            half8 bh = *(const half8*)&sKh[bo];
            half8 bl = *(const half8*)&sKl[bo];
            sacc[in] = mfma16(qh[im][kk], bh, sacc[in]);
            sacc[in] = mfma16(qh[im][kk], bl, sacc[in]);
            sacc[in] = mfma16(ql[im][kk], bh, sacc[in]);
          }
        if (kb >= 2 * qt) {  // diagonal region: mask t > s (global indices)
#pragma unroll
          for (int in = 0; in < 4; ++in)
#pragma unroll
            for (int r = 0; r < 4; ++r) {
              int sg = q0 + wave * 32 + im * 16 + quad * 4 + r;
              int tg = t0 + in * 16 + l15;
              if (tg > sg) sacc[in][r] = -1e30f;
            }
        }
        float alpha[4];
#pragma unroll
        for (int r = 0; r < 4; ++r) {
          float mx = fmaxf(fmaxf(sacc[0][r], sacc[1][r]),
                           fmaxf(sacc[2][r], sacc[3][r]));
#pragma unroll
          for (int off = 1; off < 16; off <<= 1)
            mx = fmaxf(mx, __shfl_xor(mx, off, 64));
          float mnew = fmaxf(m_st[im][r], mx);
          alpha[r] = __expf(m_st[im][r] - mnew);
          float sum = 0.0f;
#pragma unroll
          for (int in = 0; in < 4; ++in) {
            float p = __expf(sacc[in][r] - mnew);
            sacc[in][r] = p;
            sum += p;
          }
#pragma unroll
          for (int off = 1; off < 16; off <<= 1)
            sum += __shfl_xor(sum, off, 64);
          l_st[im][r] = l_st[im][r] * alpha[r] + sum;
          m_st[im][r] = mnew;
        }
#pragma unroll
        for (int in = 0; in < 4; ++in)
#pragma unroll
          for (int r = 0; r < 4; ++r)
            sP[(wave * 32 + im * 16 + quad * 4 + r) * 72 + in * 16 + l15] =
                (half_t)sacc[in][r];
#pragma unroll
        for (int iv = 0; iv < 8; ++iv)
#pragma unroll
          for (int r = 0; r < 4; ++r) oacc[im][iv][r] *= alpha[r];
      }
      // ---- O += P @ V (wave-private P; vb read once, used for both im) ----
#pragma unroll
      for (int kk2 = 0; kk2 < 2; ++kk2) {
        half8 pa0 =
            *(const half8*)&sP[(wave * 32 + l15) * 72 + kk2 * 32 + quad * 8];
        half8 pa1 = *(const half8*)&sP[(wave * 32 + 16 + l15) * 72 +
                                       kk2 * 32 + quad * 8];
#pragma unroll
        for (int iv = 0; iv < 8; ++iv) {
          half8 vb = *(const half8*)&sVt[(iv * 16 + l15) * 64 +
                                         (((kk2 * 4 + quad) ^ (l15 & 7)) * 8)];
          oacc[0][iv] = mfma16(pa0, vb, oacc[0][iv]);
          oacc[1][iv] = mfma16(pa1, vb, oacc[1][iv]);
        }
      }
    }
    __syncthreads();  // protect sK/sV before next staging
  }
  // epilogue
#pragma unroll
  for (int im = 0; im < 2; ++im) {
    float invl[4];
#pragma unroll
    for (int r = 0; r < 4; ++r) invl[r] = 1.0f / l_st[im][r];
#pragma unroll
    for (int iv = 0; iv < 8; ++iv)
#pragma unroll
      for (int r = 0; r < 4; ++r) {
        int row = q0 + wave * 32 + im * 16 + quad * 4 + r;
        int col = h * 128 + iv * 16 + l15;
        Ybig[(size_t)row * 2048 + col] = (half_t)(oacc[im][iv][r] * invl[r]);
      }
  }
}

// ---------------------------------------------------------------------------
extern "C" void kernel_launch(void* const* d_in, const int* in_sizes, int n_in,
                              void* d_out, int out_size, void* d_ws,
                              size_t ws_size, hipStream_t stream) {
  const float* x = (const float*)d_in[0];
  const float* q = (const float*)d_in[1];
  const float* k = (const float*)d_in[2];
  const float* v = (const float*)d_in[3];
  const float* o = (const float*)d_in[4];
  const float* theta = (const float*)d_in[5];
  float* out = (float*)d_out;

  char* ws = (char*)d_ws;
  const size_t HB = (size_t)2048 * 2048 * 2;  // 8 MiB
  half_t* Xh  = (half_t*)(ws);
  half_t* Xl  = (half_t*)(ws + HB);
  half_t* WTh = (half_t*)(ws + 2 * HB);  // [2][16][128][2048]; reused as Rh
  half_t* WTl = (half_t*)(ws + 4 * HB);  // reused as Rl
  half_t* VhT = (half_t*)(ws + 6 * HB);  // [16][128][2048]
  half_t* OT  = (half_t*)(ws + 7 * HB);  // [2048 d][2048 hv]
  float*  Craw = (float*)(ws + 8 * HB);  // [2][16][2048][128] fp32
  half_t* Rh = WTh;
  half_t* Rl = WTl;
  half_t* VST  = (half_t*)(ws + 8 * HB); // overlays Craw (dead after rope)
  half_t* Ybig = (half_t*)(ws + 9 * HB);

  k_split4<<<4096, 256, 0, stream>>>(x, Xh, Xl, (2048 * 2048) / 4);
  k_transpose<<<dim3(4, 64, 16), 256, 0, stream>>>(q, WTh, WTl, 2048, 128);
  k_transpose<<<dim3(4, 64, 16), 256, 0, stream>>>(
      k, WTh + (size_t)16 * 128 * 2048, WTl + (size_t)16 * 128 * 2048, 2048, 128);
  k_transpose<<<dim3(4, 64, 16), 256, 0, stream>>>(v, VhT, nullptr, 2048, 128);
  k_transpose<<<dim3(64, 64, 1), 256, 0, stream>>>(o, OT, nullptr, 2048, 2048);
  k_proj<<<dim3(16, 32), 256, 0, stream>>>(Xh, Xl, WTh, WTl, Craw);
  k_rope<<<dim3(512, 16, 2), 256, 0, stream>>>(Craw, Rh, Rl, theta);
  k_gemm1<1><<<dim3(16, 16), 256, 0, stream>>>(VhT, Xh, VST, 1.0f);
  k_flash<<<256, 256, 0, stream>>>(Rh, Rl, VST, Ybig);
  k_gemm1<0><<<dim3(16, 16), 256, 0, stream>>>(Ybig, OT, out, 1.0f / 2048.0f);
}

// Round 3
// 413.549 us; speedup vs baseline: 1.2015x; 1.1399x over previous
//
#include <hip/hip_runtime.h>
#include <math.h>

// ---------------------------------------------------------------------------
// ShrdMHAttention: z = (sum_h softmax_causal(rope(xQ) rope(xK)^T) (xV) O_h) * scale
// SEQ=2048, D_MODEL=2048, NH=16, DQK=DV=128.
//
// Precision: q/k proj and QK^T use 2-term fp16 split (hh+hl+lh); v/PV/out are
// single fp16.  Measured absmax 0.031 vs 0.102 threshold (R1/R2).
//
// R3 flash rework: BM=64, 512 blocks (2/CU, 57KB LDS) with complementary
// qt ordering (CU c gets qt=31-(c>>4) and qt=(c>>4): 33 k-iters uniform);
// DPP butterfly softmax reductions (VALU latency) instead of ds_swizzle.
// ---------------------------------------------------------------------------

typedef _Float16 half_t;
typedef __attribute__((ext_vector_type(8))) _Float16 half8;
typedef __attribute__((ext_vector_type(4))) float f32x4;

#define SEQ   2048
#define DM    2048
#define NHEAD 16

__device__ __forceinline__ f32x4 mfma16(half8 a, half8 b, f32x4 c) {
  return __builtin_amdgcn_mfma_f32_16x16x32_f16(a, b, c, 0, 0, 0);
}

__device__ __forceinline__ void gll16(const half_t* g, half_t* l) {
  __builtin_amdgcn_global_load_lds(
      (const __attribute__((address_space(1))) unsigned int*)g,
      (__attribute__((address_space(3))) unsigned int*)l, 16, 0, 0);
}

// DPP lane-permute within contiguous 16-lane rows (VALU, no LDS pipe).
template <int CTRL>
__device__ __forceinline__ float dppf(float v) {
  int r = __builtin_amdgcn_mov_dpp(__builtin_bit_cast(int, v), CTRL, 0xF, 0xF,
                                   true);
  return __builtin_bit_cast(float, r);
}
// 16-lane butterfly allreduce: xor1, xor2, mirror-in-8, mirror-in-16.
__device__ __forceinline__ float red16_max(float v) {
  v = fmaxf(v, dppf<0xB1>(v));   // quad_perm [1,0,3,2]
  v = fmaxf(v, dppf<0x4E>(v));   // quad_perm [2,3,0,1]
  v = fmaxf(v, dppf<0x141>(v));  // row_half_mirror
  v = fmaxf(v, dppf<0x140>(v));  // row_mirror
  return v;
}
__device__ __forceinline__ float red16_sum(float v) {
  v += dppf<0xB1>(v);
  v += dppf<0x4E>(v);
  v += dppf<0x141>(v);
  v += dppf<0x140>(v);
  return v;
}

// ---------------------------------------------------------------------------
__global__ __launch_bounds__(256)
void k_split4(const float* __restrict__ in, half_t* __restrict__ hi,
              half_t* __restrict__ lo, int n4) {
  int i = blockIdx.x * 256 + threadIdx.x;
  if (i >= n4) return;
  float4 v = ((const float4*)in)[i];
  union { half_t h[4]; uint2 u; } H, L;
  H.h[0] = (half_t)v.x; H.h[1] = (half_t)v.y;
  H.h[2] = (half_t)v.z; H.h[3] = (half_t)v.w;
  L.h[0] = (half_t)(v.x - (float)H.h[0]);
  L.h[1] = (half_t)(v.y - (float)H.h[1]);
  L.h[2] = (half_t)(v.z - (float)H.h[2]);
  L.h[3] = (half_t)(v.w - (float)H.h[3]);
  *(uint2*)&hi[(size_t)i * 4] = H.u;
  *(uint2*)&lo[(size_t)i * 4] = L.u;
}

// ---------------------------------------------------------------------------
__global__ __launch_bounds__(256)
void k_transpose(const float* __restrict__ in, half_t* __restrict__ hi,
                 half_t* __restrict__ lo, int R, int C) {
  __shared__ float tile[32][33];
  size_t bo = (size_t)blockIdx.z * R * C;
  int c0 = blockIdx.x * 32, r0 = blockIdx.y * 32;
  int tx = threadIdx.x & 31, ty = threadIdx.x >> 5;
#pragma unroll
  for (int i = 0; i < 32; i += 8)
    tile[ty + i][tx] = in[bo + (size_t)(r0 + ty + i) * C + c0 + tx];
  __syncthreads();
#pragma unroll
  for (int i = 0; i < 32; i += 8) {
    float v = tile[tx][ty + i];
    half_t h = (half_t)v;
    size_t oidx = bo + (size_t)(c0 + ty + i) * R + r0 + tx;
    hi[oidx] = h;
    if (lo) lo[oidx] = (half_t)(v - (float)h);
  }
}

// ---------------------------------------------------------------------------
// GEMM LDS tiles: rows of 32 halfs = 4 chunks of 16B, XOR chunk swizzle.
__device__ __forceinline__ int gemm_scol(int lane) {
  return (((lane & 3) ^ ((lane >> 3) & 3)) * 8);
}
__device__ __forceinline__ int gemm_fo(int row, int quad, int l15) {
  return row * 32 + ((quad ^ ((l15 >> 1) & 3)) * 8);
}

// Split-fp16 projection (3-term).  BM=BN=128, BK=32, 4 waves (2x2).
__global__ __launch_bounds__(256)
void k_proj(const half_t* __restrict__ Xh, const half_t* __restrict__ Xl,
            const half_t* __restrict__ WTh, const half_t* __restrict__ WTl,
            float* __restrict__ Craw) {
  __shared__ __align__(16) half_t sAh[128 * 32], sAl[128 * 32];
  __shared__ __align__(16) half_t sBh[128 * 32], sBl[128 * 32];
  int y = blockIdx.y;
  int m0 = blockIdx.x * 128;
  const half_t* wth = WTh + (size_t)y * 128 * DM;
  const half_t* wtl = WTl + (size_t)y * 128 * DM;
  int lane = threadIdx.x & 63, wave = threadIdx.x >> 6;
  int l15 = lane & 15, quad = lane >> 4;
  int wm = wave >> 1, wn = wave & 1;
  int srow = lane >> 2, scol = gemm_scol(lane);

  f32x4 acc[4][4];
#pragma unroll
  for (int a = 0; a < 4; ++a)
#pragma unroll
    for (int b = 0; b < 4; ++b) acc[a][b] = (f32x4)0.0f;

  for (int kt = 0; kt < DM / 32; ++kt) {
    int k0 = kt * 32;
#pragma unroll
    for (int i = 0; i < 2; ++i) {
      int c = wave * 2 + i;
      size_t ro = (size_t)(c * 16 + srow) * DM + k0 + scol;
      gll16(Xh + (size_t)m0 * DM + ro, sAh + c * 512);
      gll16(Xl + (size_t)m0 * DM + ro, sAl + c * 512);
      gll16(wth + ro, sBh + c * 512);
      gll16(wtl + ro, sBl + c * 512);
    }
    __syncthreads();
    half8 ah[4], al[4], bh[4], bl[4];
#pragma unroll
    for (int t = 0; t < 4; ++t) {
      int ao = gemm_fo(wm * 64 + t * 16 + l15, quad, l15);
      int bo = gemm_fo(wn * 64 + t * 16 + l15, quad, l15);
      ah[t] = *(const half8*)&sAh[ao];
      al[t] = *(const half8*)&sAl[ao];
      bh[t] = *(const half8*)&sBh[bo];
      bl[t] = *(const half8*)&sBl[bo];
    }
#pragma unroll
    for (int im = 0; im < 4; ++im)
#pragma unroll
      for (int in = 0; in < 4; ++in) {
        acc[im][in] = mfma16(ah[im], bh[in], acc[im][in]);
        acc[im][in] = mfma16(ah[im], bl[in], acc[im][in]);
        acc[im][in] = mfma16(al[im], bh[in], acc[im][in]);
      }
    __syncthreads();
  }
  float* cb = Craw + (size_t)y * SEQ * 128;
#pragma unroll
  for (int im = 0; im < 4; ++im)
#pragma unroll
    for (int in = 0; in < 4; ++in)
#pragma unroll
      for (int r = 0; r < 4; ++r) {
        int row = m0 + wm * 64 + im * 16 + quad * 4 + r;
        int col = wn * 64 + in * 16 + l15;
        cb[(size_t)row * 128 + col] = acc[im][in][r];
      }
}

// ---------------------------------------------------------------------------
__global__ __launch_bounds__(256)
void k_rope(const float* __restrict__ Craw, half_t* __restrict__ Rh,
            half_t* __restrict__ Rl, const float* __restrict__ thetap) {
  int which = blockIdx.z, h = blockIdx.y;
  int s = blockIdx.x * 4 + (threadIdx.x >> 6);
  int e = threadIdx.x & 63;
  float th = thetap[0];
  size_t base = ((size_t)(which * NHEAD + h) * SEQ + s) * 128;
  float x1 = Craw[base + e];
  float x2 = Craw[base + 64 + e];
  float rate = th * (-(float)e * (1.0f / 64.0f));
  float rot = (float)s * rate;
  float sn = sinf(rot), cs = cosf(rot);
  const float inv4 = 0.2973017787506803f;  // 128^-0.25
  float y1 = (cs * x1 - sn * x2) * inv4;
  float y2 = (sn * x1 + cs * x2) * inv4;
  half_t h1 = (half_t)y1, h2 = (half_t)y2;
  Rh[base + e] = h1;       Rl[base + e] = (half_t)(y1 - (float)h1);
  Rh[base + 64 + e] = h2;  Rl[base + 64 + e] = (half_t)(y2 - (float)h2);
}

// ---------------------------------------------------------------------------
template <int HALF_OUT>
__global__ __launch_bounds__(256)
void k_gemm1(const half_t* __restrict__ A, const half_t* __restrict__ B,
             void* __restrict__ Cv, float scale) {
  __shared__ __align__(16) half_t sA[128 * 32], sB[128 * 32];
  int am0 = blockIdx.y * 128, bn0 = blockIdx.x * 128;
  int lane = threadIdx.x & 63, wave = threadIdx.x >> 6;
  int l15 = lane & 15, quad = lane >> 4;
  int wm = wave >> 1, wn = wave & 1;
  int srow = lane >> 2, scol = gemm_scol(lane);

  f32x4 acc[4][4];
#pragma unroll
  for (int a = 0; a < 4; ++a)
#pragma unroll
    for (int b = 0; b < 4; ++b) acc[a][b] = (f32x4)0.0f;

  for (int kt = 0; kt < DM / 32; ++kt) {
    int k0 = kt * 32;
#pragma unroll
    for (int i = 0; i < 2; ++i) {
      int c = wave * 2 + i;
      size_t ro = (size_t)(c * 16 + srow) * 2048 + k0 + scol;
      gll16(A + (size_t)am0 * 2048 + ro, sA + c * 512);
      gll16(B + (size_t)bn0 * 2048 + ro, sB + c * 512);
    }
    __syncthreads();
    half8 ah[4], bh[4];
#pragma unroll
    for (int t = 0; t < 4; ++t) {
      ah[t] = *(const half8*)&sA[gemm_fo(wm * 64 + t * 16 + l15, quad, l15)];
      bh[t] = *(const half8*)&sB[gemm_fo(wn * 64 + t * 16 + l15, quad, l15)];
    }
#pragma unroll
    for (int im = 0; im < 4; ++im)
#pragma unroll
      for (int in = 0; in < 4; ++in)
        acc[im][in] = mfma16(ah[im], bh[in], acc[im][in]);
    __syncthreads();
  }
#pragma unroll
  for (int im = 0; im < 4; ++im)
#pragma unroll
    for (int in = 0; in < 4; ++in)
#pragma unroll
      for (int r = 0; r < 4; ++r) {
        int row = am0 + wm * 64 + im * 16 + quad * 4 + r;
        int col = bn0 + wn * 64 + in * 16 + l15;
        if (HALF_OUT)
          ((half_t*)Cv)[(size_t)row * 2048 + col] = (half_t)(acc[im][in][r] * scale);
        else
          ((float*)Cv)[(size_t)row * 2048 + col] = acc[im][in][r] * scale;
      }
}

// ---------------------------------------------------------------------------
// Flash attention, causal.  BM=BN=64, wave owns 16 q-rows.
// Grid 512 = 32 qtiles x 16 heads, ordered so CU c (blocks c, c+256) gets
// complementary qtiles (31-(c>>4)) and (c>>4): uniform 33 k-iters per CU.
// LDS 57.3KB -> 2 blocks/CU (8 waves/CU TLP).  DPP softmax reductions.
__global__ __launch_bounds__(256, 2)
void k_flash(const half_t* __restrict__ Rh, const half_t* __restrict__ Rl,
             const half_t* __restrict__ VST, half_t* __restrict__ Ybig) {
  int idx = blockIdx.x;
  int h = idx & 15;
  int qt = (idx < 256) ? (31 - (idx >> 4)) : ((idx - 256) >> 4);
  int lane = threadIdx.x & 63, wave = threadIdx.x >> 6;
  int l15 = lane & 15, quad = lane >> 4;

  const half_t* RQh = Rh + (size_t)h * SEQ * 128;
  const half_t* RQl = Rl + (size_t)h * SEQ * 128;
  const half_t* RKh = Rh + (size_t)(NHEAD + h) * SEQ * 128;
  const half_t* RKl = Rl + (size_t)(NHEAD + h) * SEQ * 128;
  const half_t* Vt  = VST + (size_t)h * 128 * SEQ;  // [v][t]

  __shared__ __align__(16) half_t sKh[64 * 128];
  __shared__ __align__(16) half_t sKl[64 * 128];
  __shared__ __align__(16) half_t sVt[128 * 64];
  __shared__ __align__(16) half_t sP[64 * 72];

  int q0 = qt * 64;

  // Q fragments direct from global (one-time, L2-resident)
  half8 qh[4], ql[4];
#pragma unroll
  for (int kk = 0; kk < 4; ++kk) {
    size_t ad = (size_t)(q0 + wave * 16 + l15) * 128 + kk * 32 + quad * 8;
    qh[kk] = *(const half8*)&RQh[ad];
    ql[kk] = *(const half8*)&RQl[ad];
  }

  float m_st[4], l_st[4];
  f32x4 oacc[8];
#pragma unroll
  for (int r = 0; r < 4; ++r) { m_st[r] = -INFINITY; l_st[r] = 0.0f; }
#pragma unroll
  for (int iv = 0; iv < 8; ++iv) oacc[iv] = (f32x4)0.0f;

  int nkb = qt + 1;
  for (int kb = 0; kb < nkb; ++kb) {
    int t0 = kb * 64;
    // ---- stage K (hi+lo) and V, XOR chunk-swizzled ----
#pragma unroll
    for (int i = 0; i < 4; ++i) {
      int c = wave * 4 + i;
      int rk = c * 4 + (lane >> 4);       // K row 0..63 (16 chunks/row)
      int ck = (lane & 15) ^ (rk & 15);
      gll16(RKh + (size_t)(t0 + rk) * 128 + ck * 8, sKh + c * 512);
      gll16(RKl + (size_t)(t0 + rk) * 128 + ck * 8, sKl + c * 512);
      int rv = c * 8 + (lane >> 3);       // V row 0..127 (8 chunks/row)
      int cv = (lane & 7) ^ (rv & 7);
      gll16(Vt + (size_t)rv * SEQ + t0 + cv * 8, sVt + c * 512);
    }
    __syncthreads();

    // ---- S = Q K^T (split 3-term), wave rows, cols 0..63 ----
    f32x4 sacc[4];
#pragma unroll
    for (int in = 0; in < 4; ++in) sacc[in] = (f32x4)0.0f;
#pragma unroll
    for (int kk = 0; kk < 4; ++kk)
#pragma unroll
      for (int in = 0; in < 4; ++in) {
        int bo = (in * 16 + l15) * 128 + (((kk * 4 + quad) ^ l15) * 8);
        half8 bh = *(const half8*)&sKh[bo];
        half8 bl = *(const half8*)&sKl[bo];
        sacc[in] = mfma16(qh[kk], bh, sacc[in]);
        sacc[in] = mfma16(qh[kk], bl, sacc[in]);
        sacc[in] = mfma16(ql[kk], bh, sacc[in]);
      }
    if (kb == qt) {  // diagonal block: mask t > s (local indices)
#pragma unroll
      for (int in = 0; in < 4; ++in)
#pragma unroll
        for (int r = 0; r < 4; ++r)
          if (in * 16 + l15 > wave * 16 + quad * 4 + r) sacc[in][r] = -1e30f;
    }
    // ---- online softmax: DPP 16-lane butterflies ----
    float alpha[4];
#pragma unroll
    for (int r = 0; r < 4; ++r) {
      float mx = fmaxf(fmaxf(sacc[0][r], sacc[1][r]),
                       fmaxf(sacc[2][r], sacc[3][r]));
      mx = red16_max(mx);
      float mnew = fmaxf(m_st[r], mx);
      alpha[r] = __expf(m_st[r] - mnew);
      float sum = 0.0f;
#pragma unroll
      for (int in = 0; in < 4; ++in) {
        float p = __expf(sacc[in][r] - mnew);
        sacc[in][r] = p;
        sum += p;
      }
      sum = red16_sum(sum);
      l_st[r] = l_st[r] * alpha[r] + sum;
      m_st[r] = mnew;
    }
    // ---- P to LDS (wave-private rows), rescale O ----
#pragma unroll
    for (int in = 0; in < 4; ++in)
#pragma unroll
      for (int r = 0; r < 4; ++r)
        sP[(wave * 16 + quad * 4 + r) * 72 + in * 16 + l15] =
            (half_t)sacc[in][r];
#pragma unroll
    for (int iv = 0; iv < 8; ++iv)
#pragma unroll
      for (int r = 0; r < 4; ++r) oacc[iv][r] *= alpha[r];

    // ---- O += P @ V ----
#pragma unroll
    for (int kk2 = 0; kk2 < 2; ++kk2) {
      half8 pa =
          *(const half8*)&sP[(wave * 16 + l15) * 72 + kk2 * 32 + quad * 8];
#pragma unroll
      for (int iv = 0; iv < 8; ++iv) {
        half8 vb = *(const half8*)&sVt[(iv * 16 + l15) * 64 +
                                       (((kk2 * 4 + quad) ^ (l15 & 7)) * 8)];
        oacc[iv] = mfma16(pa, vb, oacc[iv]);
      }
    }
    __syncthreads();  // protect sK/sV before next staging
  }
  // epilogue
  float invl[4];
#pragma unroll
  for (int r = 0; r < 4; ++r) invl[r] = 1.0f / l_st[r];
#pragma unroll
  for (int iv = 0; iv < 8; ++iv)
#pragma unroll
    for (int r = 0; r < 4; ++r) {
      int row = q0 + wave * 16 + quad * 4 + r;
      int col = h * 128 + iv * 16 + l15;
      Ybig[(size_t)row * 2048 + col] = (half_t)(oacc[iv][r] * invl[r]);
    }
}

// ---------------------------------------------------------------------------
extern "C" void kernel_launch(void* const* d_in, const int* in_sizes, int n_in,
                              void* d_out, int out_size, void* d_ws,
                              size_t ws_size, hipStream_t stream) {
  const float* x = (const float*)d_in[0];
  const float* q = (const float*)d_in[1];
  const float* k = (const float*)d_in[2];
  const float* v = (const float*)d_in[3];
  const float* o = (const float*)d_in[4];
  const float* theta = (const float*)d_in[5];
  float* out = (float*)d_out;

  char* ws = (char*)d_ws;
  const size_t HB = (size_t)2048 * 2048 * 2;  // 8 MiB
  half_t* Xh  = (half_t*)(ws);
  half_t* Xl  = (half_t*)(ws + HB);
  half_t* WTh = (half_t*)(ws + 2 * HB);  // [2][16][128][2048]; reused as Rh
  half_t* WTl = (half_t*)(ws + 4 * HB);  // reused as Rl
  half_t* VhT = (half_t*)(ws + 6 * HB);  // [16][128][2048]
  half_t* OT  = (half_t*)(ws + 7 * HB);  // [2048 d][2048 hv]
  float*  Craw = (float*)(ws + 8 * HB);  // [2][16][2048][128] fp32
  half_t* Rh = WTh;
  half_t* Rl = WTl;
  half_t* VST  = (half_t*)(ws + 8 * HB); // overlays Craw (dead after rope)
  half_t* Ybig = (half_t*)(ws + 9 * HB);

  k_split4<<<4096, 256, 0, stream>>>(x, Xh, Xl, (2048 * 2048) / 4);
  k_transpose<<<dim3(4, 64, 16), 256, 0, stream>>>(q, WTh, WTl, 2048, 128);
  k_transpose<<<dim3(4, 64, 16), 256, 0, stream>>>(
      k, WTh + (size_t)16 * 128 * 2048, WTl + (size_t)16 * 128 * 2048, 2048, 128);
  k_transpose<<<dim3(4, 64, 16), 256, 0, stream>>>(v, VhT, nullptr, 2048, 128);
  k_transpose<<<dim3(64, 64, 1), 256, 0, stream>>>(o, OT, nullptr, 2048, 2048);
  k_proj<<<dim3(16, 32), 256, 0, stream>>>(Xh, Xl, WTh, WTl, Craw);
  k_rope<<<dim3(512, 16, 2), 256, 0, stream>>>(Craw, Rh, Rl, theta);
  k_gemm1<1><<<dim3(16, 16), 256, 0, stream>>>(VhT, Xh, VST, 1.0f);
  k_flash<<<512, 256, 0, stream>>>(Rh, Rl, VST, Ybig);
  k_gemm1<0><<<dim3(16, 16), 256, 0, stream>>>(Ybig, OT, out, 1.0f / 2048.0f);
}

// Round 4
// 380.946 us; speedup vs baseline: 1.3044x; 1.0856x over previous
//
#include <hip/hip_runtime.h>
#include <math.h>

// ---------------------------------------------------------------------------
// ShrdMHAttention: z = (sum_h softmax_causal(rope(xQ) rope(xK)^T) (xV) O_h) * scale
// SEQ=2048, D_MODEL=2048, NH=16, DQK=DV=128.
//
// Precision: q/k proj and QK^T use 2-term fp16 split (hh+hl+lh); v/PV/out are
// single fp16.  Measured absmax 0.031 vs 0.102 threshold (R1-R3).
//
// R4: BK=64 in proj/gemm1 (96 MFMA per barrier pair; LDS 64/32 KB, occupancy
// grid-capped so no loss); rope dedupes trig per (s,e) and uses f64 mod-2pi
// reduction + small-arg sinf/cosf instead of 8.4M Payne-Hanek calls.
// ---------------------------------------------------------------------------

typedef _Float16 half_t;
typedef __attribute__((ext_vector_type(8))) _Float16 half8;
typedef __attribute__((ext_vector_type(4))) float f32x4;

#define SEQ   2048
#define DM    2048
#define NHEAD 16

__device__ __forceinline__ f32x4 mfma16(half8 a, half8 b, f32x4 c) {
  return __builtin_amdgcn_mfma_f32_16x16x32_f16(a, b, c, 0, 0, 0);
}

__device__ __forceinline__ void gll16(const half_t* g, half_t* l) {
  __builtin_amdgcn_global_load_lds(
      (const __attribute__((address_space(1))) unsigned int*)g,
      (__attribute__((address_space(3))) unsigned int*)l, 16, 0, 0);
}

// DPP lane-permute within contiguous 16-lane rows (VALU, no LDS pipe).
template <int CTRL>
__device__ __forceinline__ float dppf(float v) {
  int r = __builtin_amdgcn_mov_dpp(__builtin_bit_cast(int, v), CTRL, 0xF, 0xF,
                                   true);
  return __builtin_bit_cast(float, r);
}
__device__ __forceinline__ float red16_max(float v) {
  v = fmaxf(v, dppf<0xB1>(v));   // quad_perm [1,0,3,2]
  v = fmaxf(v, dppf<0x4E>(v));   // quad_perm [2,3,0,1]
  v = fmaxf(v, dppf<0x141>(v));  // row_half_mirror
  v = fmaxf(v, dppf<0x140>(v));  // row_mirror
  return v;
}
__device__ __forceinline__ float red16_sum(float v) {
  v += dppf<0xB1>(v);
  v += dppf<0x4E>(v);
  v += dppf<0x141>(v);
  v += dppf<0x140>(v);
  return v;
}

// ---------------------------------------------------------------------------
__global__ __launch_bounds__(256)
void k_split4(const float* __restrict__ in, half_t* __restrict__ hi,
              half_t* __restrict__ lo, int n4) {
  int i = blockIdx.x * 256 + threadIdx.x;
  if (i >= n4) return;
  float4 v = ((const float4*)in)[i];
  union { half_t h[4]; uint2 u; } H, L;
  H.h[0] = (half_t)v.x; H.h[1] = (half_t)v.y;
  H.h[2] = (half_t)v.z; H.h[3] = (half_t)v.w;
  L.h[0] = (half_t)(v.x - (float)H.h[0]);
  L.h[1] = (half_t)(v.y - (float)H.h[1]);
  L.h[2] = (half_t)(v.z - (float)H.h[2]);
  L.h[3] = (half_t)(v.w - (float)H.h[3]);
  *(uint2*)&hi[(size_t)i * 4] = H.u;
  *(uint2*)&lo[(size_t)i * 4] = L.u;
}

// ---------------------------------------------------------------------------
__global__ __launch_bounds__(256)
void k_transpose(const float* __restrict__ in, half_t* __restrict__ hi,
                 half_t* __restrict__ lo, int R, int C) {
  __shared__ float tile[32][33];
  size_t bo = (size_t)blockIdx.z * R * C;
  int c0 = blockIdx.x * 32, r0 = blockIdx.y * 32;
  int tx = threadIdx.x & 31, ty = threadIdx.x >> 5;
#pragma unroll
  for (int i = 0; i < 32; i += 8)
    tile[ty + i][tx] = in[bo + (size_t)(r0 + ty + i) * C + c0 + tx];
  __syncthreads();
#pragma unroll
  for (int i = 0; i < 32; i += 8) {
    float v = tile[tx][ty + i];
    half_t h = (half_t)v;
    size_t oidx = bo + (size_t)(c0 + ty + i) * R + r0 + tx;
    hi[oidx] = h;
    if (lo) lo[oidx] = (half_t)(v - (float)h);
  }
}

// ---------------------------------------------------------------------------
// BK=64 tiles: rows of 64 halfs = 8 chunks of 16B.  XOR swizzle key row&7.
// Staging pass i (i=0..3 per array): chunk id g = (wave*4+i)*64+lane,
// row = g>>3, logical chunk = (g&7)^(row&7).  Frag read: chunk
// (kk*4+quad)^(row&7) -> uniform 8 words/bank per ds_read_b128 (b128 minimum).

// Split-fp16 projection (3-term).  BM=BN=128, BK=64, 4 waves (2x2).
__global__ __launch_bounds__(256, 2)
void k_proj(const half_t* __restrict__ Xh, const half_t* __restrict__ Xl,
            const half_t* __restrict__ WTh, const half_t* __restrict__ WTl,
            float* __restrict__ Craw) {
  __shared__ __align__(16) half_t sAh[128 * 64], sAl[128 * 64];
  __shared__ __align__(16) half_t sBh[128 * 64], sBl[128 * 64];
  int y = blockIdx.y;
  int m0 = blockIdx.x * 128;
  const half_t* wth = WTh + (size_t)y * 128 * DM;
  const half_t* wtl = WTl + (size_t)y * 128 * DM;
  int lane = threadIdx.x & 63, wave = threadIdx.x >> 6;
  int l15 = lane & 15, quad = lane >> 4;
  int wm = wave >> 1, wn = wave & 1;

  f32x4 acc[4][4];
#pragma unroll
  for (int a = 0; a < 4; ++a)
#pragma unroll
    for (int b = 0; b < 4; ++b) acc[a][b] = (f32x4)0.0f;

  for (int kt = 0; kt < DM / 64; ++kt) {
    int k0 = kt * 64;
#pragma unroll
    for (int i = 0; i < 4; ++i) {
      int c = wave * 4 + i;
      int g = c * 64 + lane;
      int row = g >> 3;
      int lc = (g & 7) ^ (row & 7);
      size_t ro = (size_t)row * DM + k0 + lc * 8;
      gll16(Xh + (size_t)m0 * DM + ro, sAh + c * 512);
      gll16(Xl + (size_t)m0 * DM + ro, sAl + c * 512);
      gll16(wth + ro, sBh + c * 512);
      gll16(wtl + ro, sBl + c * 512);
    }
    __syncthreads();
#pragma unroll
    for (int kk = 0; kk < 2; ++kk) {
      half8 ah[4], al[4], bh[4], bl[4];
#pragma unroll
      for (int t = 0; t < 4; ++t) {
        int ar = wm * 64 + t * 16 + l15;
        int br = wn * 64 + t * 16 + l15;
        int ao = ar * 64 + (((kk * 4 + quad) ^ (ar & 7)) * 8);
        int bo = br * 64 + (((kk * 4 + quad) ^ (br & 7)) * 8);
        ah[t] = *(const half8*)&sAh[ao];
        al[t] = *(const half8*)&sAl[ao];
        bh[t] = *(const half8*)&sBh[bo];
        bl[t] = *(const half8*)&sBl[bo];
      }
#pragma unroll
      for (int im = 0; im < 4; ++im)
#pragma unroll
        for (int in = 0; in < 4; ++in) {
          acc[im][in] = mfma16(ah[im], bh[in], acc[im][in]);
          acc[im][in] = mfma16(ah[im], bl[in], acc[im][in]);
          acc[im][in] = mfma16(al[im], bh[in], acc[im][in]);
        }
    }
    __syncthreads();
  }
  float* cb = Craw + (size_t)y * SEQ * 128;
#pragma unroll
  for (int im = 0; im < 4; ++im)
#pragma unroll
    for (int in = 0; in < 4; ++in)
#pragma unroll
      for (int r = 0; r < 4; ++r) {
        int row = m0 + wm * 64 + im * 16 + quad * 4 + r;
        int col = wn * 64 + in * 16 + l15;
        cb[(size_t)row * 128 + col] = acc[im][in][r];
      }
}

// ---------------------------------------------------------------------------
// RoPE: trig once per (s,e), applied to all 32 (which,head) rows.
// rot = fp32(s * fp32(th * (-e/64))) matches numpy bit-for-bit; sin/cos via
// f64 mod-2pi reduction (err 4.4e-9) + small-arg sinf/cosf.
__global__ __launch_bounds__(256)
void k_rope(const float* __restrict__ Craw, half_t* __restrict__ Rh,
            half_t* __restrict__ Rl, const float* __restrict__ thetap) {
  int e = threadIdx.x & 63, sl = threadIdx.x >> 6;
  int s = blockIdx.x * 4 + sl;
  float th = thetap[0];
  float rate = th * (-(float)e * (1.0f / 64.0f));  // exact e/64
  float rot = (float)s * rate;                     // the value numpy takes sin of
  double rev = (double)rot * 0.15915494309189535;  // /(2*pi)
  double fr = rev - rint(rev);                     // [-0.5, 0.5] revolutions
  float thr = (float)(fr * 6.283185307179586);     // radians, |thr| <= pi
  float sn = sinf(thr), cs = cosf(thr);
  const float inv4 = 0.2973017787506803f;          // 128^-0.25
  float csn = cs * inv4, snn = sn * inv4;
#pragma unroll 4
  for (int y = 0; y < 32; ++y) {
    size_t base = ((size_t)y * SEQ + s) * 128;
    float x1 = Craw[base + e];
    float x2 = Craw[base + 64 + e];
    float y1 = csn * x1 - snn * x2;
    float y2 = snn * x1 + csn * x2;
    half_t h1 = (half_t)y1, h2 = (half_t)y2;
    Rh[base + e] = h1;       Rl[base + e] = (half_t)(y1 - (float)h1);
    Rh[base + 64 + e] = h2;  Rl[base + 64 + e] = (half_t)(y2 - (float)h2);
  }
}

// ---------------------------------------------------------------------------
// Single-term fp16 GEMM, BK=64.  C[am0+m][bn0+n] = scale * sum_k A[m][k]B[n][k].
template <int HALF_OUT>
__global__ __launch_bounds__(256)
void k_gemm1(const half_t* __restrict__ A, const half_t* __restrict__ B,
             void* __restrict__ Cv, float scale) {
  __shared__ __align__(16) half_t sA[128 * 64], sB[128 * 64];
  int am0 = blockIdx.y * 128, bn0 = blockIdx.x * 128;
  int lane = threadIdx.x & 63, wave = threadIdx.x >> 6;
  int l15 = lane & 15, quad = lane >> 4;
  int wm = wave >> 1, wn = wave & 1;

  f32x4 acc[4][4];
#pragma unroll
  for (int a = 0; a < 4; ++a)
#pragma unroll
    for (int b = 0; b < 4; ++b) acc[a][b] = (f32x4)0.0f;

  for (int kt = 0; kt < DM / 64; ++kt) {
    int k0 = kt * 64;
#pragma unroll
    for (int i = 0; i < 4; ++i) {
      int c = wave * 4 + i;
      int g = c * 64 + lane;
      int row = g >> 3;
      int lc = (g & 7) ^ (row & 7);
      size_t ro = (size_t)row * 2048 + k0 + lc * 8;
      gll16(A + (size_t)am0 * 2048 + ro, sA + c * 512);
      gll16(B + (size_t)bn0 * 2048 + ro, sB + c * 512);
    }
    __syncthreads();
#pragma unroll
    for (int kk = 0; kk < 2; ++kk) {
      half8 ah[4], bh[4];
#pragma unroll
      for (int t = 0; t < 4; ++t) {
        int ar = wm * 64 + t * 16 + l15;
        int br = wn * 64 + t * 16 + l15;
        ah[t] = *(const half8*)&sA[ar * 64 + (((kk * 4 + quad) ^ (ar & 7)) * 8)];
        bh[t] = *(const half8*)&sB[br * 64 + (((kk * 4 + quad) ^ (br & 7)) * 8)];
      }
#pragma unroll
      for (int im = 0; im < 4; ++im)
#pragma unroll
        for (int in = 0; in < 4; ++in)
          acc[im][in] = mfma16(ah[im], bh[in], acc[im][in]);
    }
    __syncthreads();
  }
#pragma unroll
  for (int im = 0; im < 4; ++im)
#pragma unroll
    for (int in = 0; in < 4; ++in)
#pragma unroll
      for (int r = 0; r < 4; ++r) {
        int row = am0 + wm * 64 + im * 16 + quad * 4 + r;
        int col = bn0 + wn * 64 + in * 16 + l15;
        if (HALF_OUT)
          ((half_t*)Cv)[(size_t)row * 2048 + col] = (half_t)(acc[im][in][r] * scale);
        else
          ((float*)Cv)[(size_t)row * 2048 + col] = acc[im][in][r] * scale;
      }
}

// ---------------------------------------------------------------------------
// Flash attention, causal.  BM=BN=64, wave owns 16 q-rows.
// Grid 512 = 32 qtiles x 16 heads, complementary qt pairing (uniform 33
// k-iters per CU).  2 blocks/CU.  DPP softmax reductions.
__global__ __launch_bounds__(256, 2)
void k_flash(const half_t* __restrict__ Rh, const half_t* __restrict__ Rl,
             const half_t* __restrict__ VST, half_t* __restrict__ Ybig) {
  int idx = blockIdx.x;
  int h = idx & 15;
  int qt = (idx < 256) ? (31 - (idx >> 4)) : ((idx - 256) >> 4);
  int lane = threadIdx.x & 63, wave = threadIdx.x >> 6;
  int l15 = lane & 15, quad = lane >> 4;

  const half_t* RQh = Rh + (size_t)h * SEQ * 128;
  const half_t* RQl = Rl + (size_t)h * SEQ * 128;
  const half_t* RKh = Rh + (size_t)(NHEAD + h) * SEQ * 128;
  const half_t* RKl = Rl + (size_t)(NHEAD + h) * SEQ * 128;
  const half_t* Vt  = VST + (size_t)h * 128 * SEQ;  // [v][t]

  __shared__ __align__(16) half_t sKh[64 * 128];
  __shared__ __align__(16) half_t sKl[64 * 128];
  __shared__ __align__(16) half_t sVt[128 * 64];
  __shared__ __align__(16) half_t sP[64 * 72];

  int q0 = qt * 64;

  // Q fragments direct from global (one-time, L2-resident)
  half8 qh[4], ql[4];
#pragma unroll
  for (int kk = 0; kk < 4; ++kk) {
    size_t ad = (size_t)(q0 + wave * 16 + l15) * 128 + kk * 32 + quad * 8;
    qh[kk] = *(const half8*)&RQh[ad];
    ql[kk] = *(const half8*)&RQl[ad];
  }

  float m_st[4], l_st[4];
  f32x4 oacc[8];
#pragma unroll
  for (int r = 0; r < 4; ++r) { m_st[r] = -INFINITY; l_st[r] = 0.0f; }
#pragma unroll
  for (int iv = 0; iv < 8; ++iv) oacc[iv] = (f32x4)0.0f;

  int nkb = qt + 1;
  for (int kb = 0; kb < nkb; ++kb) {
    int t0 = kb * 64;
#pragma unroll
    for (int i = 0; i < 4; ++i) {
      int c = wave * 4 + i;
      int rk = c * 4 + (lane >> 4);       // K row 0..63 (16 chunks/row)
      int ck = (lane & 15) ^ (rk & 15);
      gll16(RKh + (size_t)(t0 + rk) * 128 + ck * 8, sKh + c * 512);
      gll16(RKl + (size_t)(t0 + rk) * 128 + ck * 8, sKl + c * 512);
      int rv = c * 8 + (lane >> 3);       // V row 0..127 (8 chunks/row)
      int cv = (lane & 7) ^ (rv & 7);
      gll16(Vt + (size_t)rv * SEQ + t0 + cv * 8, sVt + c * 512);
    }
    __syncthreads();

    f32x4 sacc[4];
#pragma unroll
    for (int in = 0; in < 4; ++in) sacc[in] = (f32x4)0.0f;
#pragma unroll
    for (int kk = 0; kk < 4; ++kk)
#pragma unroll
      for (int in = 0; in < 4; ++in) {
        int bo = (in * 16 + l15) * 128 + (((kk * 4 + quad) ^ l15) * 8);
        half8 bh = *(const half8*)&sKh[bo];
        half8 bl = *(const half8*)&sKl[bo];
        sacc[in] = mfma16(qh[kk], bh, sacc[in]);
        sacc[in] = mfma16(qh[kk], bl, sacc[in]);
        sacc[in] = mfma16(ql[kk], bh, sacc[in]);
      }
    if (kb == qt) {  // diagonal block: mask t > s (local indices)
#pragma unroll
      for (int in = 0; in < 4; ++in)
#pragma unroll
        for (int r = 0; r < 4; ++r)
          if (in * 16 + l15 > wave * 16 + quad * 4 + r) sacc[in][r] = -1e30f;
    }
    float alpha[4];
#pragma unroll
    for (int r = 0; r < 4; ++r) {
      float mx = fmaxf(fmaxf(sacc[0][r], sacc[1][r]),
                       fmaxf(sacc[2][r], sacc[3][r]));
      mx = red16_max(mx);
      float mnew = fmaxf(m_st[r], mx);
      alpha[r] = __expf(m_st[r] - mnew);
      float sum = 0.0f;
#pragma unroll
      for (int in = 0; in < 4; ++in) {
        float p = __expf(sacc[in][r] - mnew);
        sacc[in][r] = p;
        sum += p;
      }
      sum = red16_sum(sum);
      l_st[r] = l_st[r] * alpha[r] + sum;
      m_st[r] = mnew;
    }
#pragma unroll
    for (int in = 0; in < 4; ++in)
#pragma unroll
      for (int r = 0; r < 4; ++r)
        sP[(wave * 16 + quad * 4 + r) * 72 + in * 16 + l15] =
            (half_t)sacc[in][r];
#pragma unroll
    for (int iv = 0; iv < 8; ++iv)
#pragma unroll
      for (int r = 0; r < 4; ++r) oacc[iv][r] *= alpha[r];

#pragma unroll
    for (int kk2 = 0; kk2 < 2; ++kk2) {
      half8 pa =
          *(const half8*)&sP[(wave * 16 + l15) * 72 + kk2 * 32 + quad * 8];
#pragma unroll
      for (int iv = 0; iv < 8; ++iv) {
        half8 vb = *(const half8*)&sVt[(iv * 16 + l15) * 64 +
                                       (((kk2 * 4 + quad) ^ (l15 & 7)) * 8)];
        oacc[iv] = mfma16(pa, vb, oacc[iv]);
      }
    }
    __syncthreads();
  }
  float invl[4];
#pragma unroll
  for (int r = 0; r < 4; ++r) invl[r] = 1.0f / l_st[r];
#pragma unroll
  for (int iv = 0; iv < 8; ++iv)
#pragma unroll
    for (int r = 0; r < 4; ++r) {
      int row = q0 + wave * 16 + quad * 4 + r;
      int col = h * 128 + iv * 16 + l15;
      Ybig[(size_t)row * 2048 + col] = (half_t)(oacc[iv][r] * invl[r]);
    }
}

// ---------------------------------------------------------------------------
extern "C" void kernel_launch(void* const* d_in, const int* in_sizes, int n_in,
                              void* d_out, int out_size, void* d_ws,
                              size_t ws_size, hipStream_t stream) {
  const float* x = (const float*)d_in[0];
  const float* q = (const float*)d_in[1];
  const float* k = (const float*)d_in[2];
  const float* v = (const float*)d_in[3];
  const float* o = (const float*)d_in[4];
  const float* theta = (const float*)d_in[5];
  float* out = (float*)d_out;

  char* ws = (char*)d_ws;
  const size_t HB = (size_t)2048 * 2048 * 2;  // 8 MiB
  half_t* Xh  = (half_t*)(ws);
  half_t* Xl  = (half_t*)(ws + HB);
  half_t* WTh = (half_t*)(ws + 2 * HB);  // [2][16][128][2048]; reused as Rh
  half_t* WTl = (half_t*)(ws + 4 * HB);  // reused as Rl
  half_t* VhT = (half_t*)(ws + 6 * HB);  // [16][128][2048]
  half_t* OT  = (half_t*)(ws + 7 * HB);  // [2048 d][2048 hv]
  float*  Craw = (float*)(ws + 8 * HB);  // [2][16][2048][128] fp32
  half_t* Rh = WTh;
  half_t* Rl = WTl;
  half_t* VST  = (half_t*)(ws + 8 * HB); // overlays Craw (dead after rope)
  half_t* Ybig = (half_t*)(ws + 9 * HB);

  k_split4<<<4096, 256, 0, stream>>>(x, Xh, Xl, (2048 * 2048) / 4);
  k_transpose<<<dim3(4, 64, 16), 256, 0, stream>>>(q, WTh, WTl, 2048, 128);
  k_transpose<<<dim3(4, 64, 16), 256, 0, stream>>>(
      k, WTh + (size_t)16 * 128 * 2048, WTl + (size_t)16 * 128 * 2048, 2048, 128);
  k_transpose<<<dim3(4, 64, 16), 256, 0, stream>>>(v, VhT, nullptr, 2048, 128);
  k_transpose<<<dim3(64, 64, 1), 256, 0, stream>>>(o, OT, nullptr, 2048, 2048);
  k_proj<<<dim3(16, 32), 256, 0, stream>>>(Xh, Xl, WTh, WTl, Craw);
  k_rope<<<512, 256, 0, stream>>>(Craw, Rh, Rl, theta);
  k_gemm1<1><<<dim3(16, 16), 256, 0, stream>>>(VhT, Xh, VST, 1.0f);
  k_flash<<<512, 256, 0, stream>>>(Rh, Rl, VST, Ybig);
  k_gemm1<0><<<dim3(16, 16), 256, 0, stream>>>(Ybig, OT, out, 1.0f / 2048.0f);
}

// Round 5
// 354.710 us; speedup vs baseline: 1.4008x; 1.0740x over previous
//
#include <hip/hip_runtime.h>
#include <math.h>

// ---------------------------------------------------------------------------
// ShrdMHAttention: z = (sum_h softmax_causal(rope(xQ) rope(xK)^T) (xV) O_h) * scale
// SEQ=2048, D_MODEL=2048, NH=16, DQK=DV=128.
//
// Precision: q/k proj and QK^T use 2-term fp16 split (hh+hl+lh); v/PV/out are
// single fp16.  Measured absmax 0.031 vs 0.102 threshold (R1-R4).
//
// R5: (1) RoPE+split fused into k_proj epilogue (LDS transpose exchange,
// trig from a precomputed table -> bit-identical values); (2) all
// preprocessing fused into one k_pre launch (10 kernels -> 5); (3) gemm1
// regridded to 512 blocks = 2 blocks/CU for barrier overlap.
// ---------------------------------------------------------------------------

typedef _Float16 half_t;
typedef __attribute__((ext_vector_type(8))) _Float16 half8;
typedef __attribute__((ext_vector_type(4))) float f32x4;

#define SEQ   2048
#define DM    2048
#define NHEAD 16

__device__ __forceinline__ f32x4 mfma16(half8 a, half8 b, f32x4 c) {
  return __builtin_amdgcn_mfma_f32_16x16x32_f16(a, b, c, 0, 0, 0);
}

__device__ __forceinline__ void gll16(const half_t* g, half_t* l) {
  __builtin_amdgcn_global_load_lds(
      (const __attribute__((address_space(1))) unsigned int*)g,
      (__attribute__((address_space(3))) unsigned int*)l, 16, 0, 0);
}

// DPP lane-permute within contiguous 16-lane rows (VALU, no LDS pipe).
template <int CTRL>
__device__ __forceinline__ float dppf(float v) {
  int r = __builtin_amdgcn_mov_dpp(__builtin_bit_cast(int, v), CTRL, 0xF, 0xF,
                                   true);
  return __builtin_bit_cast(float, r);
}
__device__ __forceinline__ float red16_max(float v) {
  v = fmaxf(v, dppf<0xB1>(v));   // quad_perm [1,0,3,2]
  v = fmaxf(v, dppf<0x4E>(v));   // quad_perm [2,3,0,1]
  v = fmaxf(v, dppf<0x141>(v));  // row_half_mirror
  v = fmaxf(v, dppf<0x140>(v));  // row_mirror
  return v;
}
__device__ __forceinline__ float red16_sum(float v) {
  v += dppf<0xB1>(v);
  v += dppf<0x4E>(v);
  v += dppf<0x141>(v);
  v += dppf<0x140>(v);
  return v;
}

// ---------------------------------------------------------------------------
// k_pre: one launch for x hi/lo split, q/k/v/o transposes, trig table.
//   blocks [0,4096):        x split (fp32 -> Xh/Xl)
//   blocks [4096,16384):    q/k/v transpose 2048x128 -> 128x2048 (+split q,k)
//   blocks [16384,20480):   o transpose 2048x2048
//   blocks [20480,20992):   trig table: trig[s*64+e] = {cos,sin}*128^-0.25
__device__ __forceinline__ void tpose32(const float* __restrict__ in,
                                        half_t* __restrict__ hi,
                                        half_t* __restrict__ lo, int R, int C,
                                        int r0, int c0, float (*tile)[33],
                                        int tid) {
  int tx = tid & 31, ty = tid >> 5;
#pragma unroll
  for (int i = 0; i < 32; i += 8)
    tile[ty + i][tx] = in[(size_t)(r0 + ty + i) * C + c0 + tx];
  __syncthreads();
#pragma unroll
  for (int i = 0; i < 32; i += 8) {
    float v = tile[tx][ty + i];
    half_t h = (half_t)v;
    size_t oidx = (size_t)(c0 + ty + i) * R + r0 + tx;
    hi[oidx] = h;
    if (lo) lo[oidx] = (half_t)(v - (float)h);
  }
}

__global__ __launch_bounds__(256)
void k_pre(const float* __restrict__ x, const float* __restrict__ q,
           const float* __restrict__ k, const float* __restrict__ v,
           const float* __restrict__ o, const float* __restrict__ thetap,
           half_t* __restrict__ Xh, half_t* __restrict__ Xl,
           half_t* __restrict__ WTh, half_t* __restrict__ WTl,
           half_t* __restrict__ VhT, half_t* __restrict__ OT,
           float2* __restrict__ trig) {
  __shared__ float tile[32][33];
  int b = blockIdx.x, tid = threadIdx.x;
  if (b < 4096) {
    int i = b * 256 + tid;  // n4 = 1048576 exactly
    float4 vv = ((const float4*)x)[i];
    union { half_t h[4]; uint2 u; } H, L;
    H.h[0] = (half_t)vv.x; H.h[1] = (half_t)vv.y;
    H.h[2] = (half_t)vv.z; H.h[3] = (half_t)vv.w;
    L.h[0] = (half_t)(vv.x - (float)H.h[0]);
    L.h[1] = (half_t)(vv.y - (float)H.h[1]);
    L.h[2] = (half_t)(vv.z - (float)H.h[2]);
    L.h[3] = (half_t)(vv.w - (float)H.h[3]);
    *(uint2*)&Xh[(size_t)i * 4] = H.u;
    *(uint2*)&Xl[(size_t)i * 4] = L.u;
  } else if (b < 16384) {
    int j = b - 4096;
    int which = j >> 12, z = (j >> 8) & 15, tb = j & 255;
    int c0 = (tb & 3) * 32, r0 = (tb >> 2) * 32;
    const float* src =
        (which == 0 ? q : which == 1 ? k : v) + (size_t)z * 2048 * 128;
    size_t doff = (size_t)z * 128 * 2048;
    if (which == 0)
      tpose32(src, WTh + doff, WTl + doff, 2048, 128, r0, c0, tile, tid);
    else if (which == 1) {
      size_t koff = (size_t)16 * 128 * 2048 + doff;
      tpose32(src, WTh + koff, WTl + koff, 2048, 128, r0, c0, tile, tid);
    } else
      tpose32(src, VhT + doff, nullptr, 2048, 128, r0, c0, tile, tid);
  } else if (b < 20480) {
    int j = b - 16384;
    int c0 = (j & 63) * 32, r0 = (j >> 6) * 32;
    tpose32(o, OT, nullptr, 2048, 2048, r0, c0, tile, tid);
  } else {
    int idx = (b - 20480) * 256 + tid;  // 0..131071
    int s = idx >> 6, e = idx & 63;
    float th = thetap[0];
    float rate = th * (-(float)e * (1.0f / 64.0f));  // exact e/64
    float rot = (float)s * rate;                     // value numpy takes sin of
    double rev = (double)rot * 0.15915494309189535;  // /(2*pi)
    double fr = rev - rint(rev);
    float thr = (float)(fr * 6.283185307179586);
    float sn = sinf(thr), cs = cosf(thr);
    const float inv4 = 0.2973017787506803f;          // 128^-0.25
    trig[idx] = make_float2(cs * inv4, sn * inv4);
  }
}

// ---------------------------------------------------------------------------
// Split-fp16 projection (3-term) with fused RoPE epilogue.
// BM=BN=128, BK=64, 4 waves (2x2).  Rows of 64 halfs = 8 chunks of 16B,
// XOR swizzle key row&7.  Epilogue: 2 passes of 64 rows through a padded
// f32 LDS tile to pair cols (e, e+64), then rope+scale+split -> Rh/Rl.
__global__ __launch_bounds__(256, 2)
void k_proj(const half_t* __restrict__ Xh, const half_t* __restrict__ Xl,
            const half_t* __restrict__ WTh, const half_t* __restrict__ WTl,
            const float2* __restrict__ trig, half_t* __restrict__ Rh,
            half_t* __restrict__ Rl) {
  __shared__ __align__(16) char smem[65536];
  half_t* sAh = (half_t*)smem;            // 16 KB each
  half_t* sAl = (half_t*)(smem + 16384);
  half_t* sBh = (half_t*)(smem + 32768);
  half_t* sBl = (half_t*)(smem + 49152);
  int y = blockIdx.y;
  int m0 = blockIdx.x * 128;
  const half_t* wth = WTh + (size_t)y * 128 * DM;
  const half_t* wtl = WTl + (size_t)y * 128 * DM;
  int lane = threadIdx.x & 63, wave = threadIdx.x >> 6;
  int l15 = lane & 15, quad = lane >> 4;
  int wm = wave >> 1, wn = wave & 1;

  f32x4 acc[4][4];
#pragma unroll
  for (int a = 0; a < 4; ++a)
#pragma unroll
    for (int b = 0; b < 4; ++b) acc[a][b] = (f32x4)0.0f;

  for (int kt = 0; kt < DM / 64; ++kt) {
    int k0 = kt * 64;
#pragma unroll
    for (int i = 0; i < 4; ++i) {
      int c = wave * 4 + i;
      int g = c * 64 + lane;
      int row = g >> 3;
      int lc = (g & 7) ^ (row & 7);
      size_t ro = (size_t)row * DM + k0 + lc * 8;
      gll16(Xh + (size_t)m0 * DM + ro, sAh + c * 512);
      gll16(Xl + (size_t)m0 * DM + ro, sAl + c * 512);
      gll16(wth + ro, sBh + c * 512);
      gll16(wtl + ro, sBl + c * 512);
    }
    __syncthreads();
#pragma unroll
    for (int kk = 0; kk < 2; ++kk) {
      half8 ah[4], al[4], bh[4], bl[4];
#pragma unroll
      for (int t = 0; t < 4; ++t) {
        int ar = wm * 64 + t * 16 + l15;
        int br = wn * 64 + t * 16 + l15;
        int ao = ar * 64 + (((kk * 4 + quad) ^ (ar & 7)) * 8);
        int bo = br * 64 + (((kk * 4 + quad) ^ (br & 7)) * 8);
        ah[t] = *(const half8*)&sAh[ao];
        al[t] = *(const half8*)&sAl[ao];
        bh[t] = *(const half8*)&sBh[bo];
        bl[t] = *(const half8*)&sBl[bo];
      }
#pragma unroll
      for (int im = 0; im < 4; ++im)
#pragma unroll
        for (int in = 0; in < 4; ++in) {
          acc[im][in] = mfma16(ah[im], bh[in], acc[im][in]);
          acc[im][in] = mfma16(ah[im], bl[in], acc[im][in]);
          acc[im][in] = mfma16(al[im], bh[in], acc[im][in]);
        }
    }
    __syncthreads();
  }
  // ---- fused RoPE epilogue: two 64-row passes via padded f32 tile ----
  float* tile = (float*)smem;  // 64 x 132 f32 = 33 KB
  size_t ybase = (size_t)y * SEQ * 128;
#pragma unroll
  for (int p = 0; p < 2; ++p) {
    if (p) __syncthreads();  // prev pass reads done before overwrite
    if (wm == p) {
#pragma unroll
      for (int im = 0; im < 4; ++im)
#pragma unroll
        for (int in = 0; in < 4; ++in)
#pragma unroll
          for (int r = 0; r < 4; ++r)
            tile[(im * 16 + quad * 4 + r) * 132 + wn * 64 + in * 16 + l15] =
                acc[im][in][r];
    }
    __syncthreads();
    int e = lane;  // 0..63
#pragma unroll 4
    for (int rr = 0; rr < 16; ++rr) {
      int rloc = wave * 16 + rr;
      int s = m0 + p * 64 + rloc;
      float x1 = tile[rloc * 132 + e];
      float x2 = tile[rloc * 132 + 64 + e];
      float2 sc = trig[s * 64 + e];
      float y1 = sc.x * x1 - sc.y * x2;
      float y2 = sc.y * x1 + sc.x * x2;
      half_t h1 = (half_t)y1, h2 = (half_t)y2;
      size_t base = ybase + (size_t)s * 128;
      Rh[base + e] = h1;       Rl[base + e] = (half_t)(y1 - (float)h1);
      Rh[base + 64 + e] = h2;  Rl[base + 64 + e] = (half_t)(y2 - (float)h2);
    }
  }
}

// ---------------------------------------------------------------------------
// Single-term fp16 GEMM, BM=64, BN=128, BK=64, grid (16,32) = 512 blocks
// -> 2 blocks/CU.  Wave tile 32x64 (2x2 wave grid).
template <int HALF_OUT>
__global__ __launch_bounds__(256)
void k_gemm1(const half_t* __restrict__ A, const half_t* __restrict__ B,
             void* __restrict__ Cv, float scale) {
  __shared__ __align__(16) half_t sA[64 * 64], sB[128 * 64];
  int am0 = blockIdx.y * 64, bn0 = blockIdx.x * 128;
  int lane = threadIdx.x & 63, wave = threadIdx.x >> 6;
  int l15 = lane & 15, quad = lane >> 4;
  int wm = wave >> 1, wn = wave & 1;

  f32x4 acc[2][4];
#pragma unroll
  for (int a = 0; a < 2; ++a)
#pragma unroll
    for (int b = 0; b < 4; ++b) acc[a][b] = (f32x4)0.0f;

  for (int kt = 0; kt < DM / 64; ++kt) {
    int k0 = kt * 64;
    // sA: 512 chunks in 2 passes
#pragma unroll
    for (int i = 0; i < 2; ++i) {
      int g0 = (i * 4 + wave) * 64;
      int g = g0 + lane;
      int row = g >> 3;
      int lc = (g & 7) ^ (row & 7);
      gll16(A + (size_t)(am0 + row) * 2048 + k0 + lc * 8, sA + g0 * 8);
    }
    // sB: 1024 chunks in 4 passes
#pragma unroll
    for (int i = 0; i < 4; ++i) {
      int g0 = (i * 4 + wave) * 64;
      int g = g0 + lane;
      int row = g >> 3;
      int lc = (g & 7) ^ (row & 7);
      gll16(B + (size_t)(bn0 + row) * 2048 + k0 + lc * 8, sB + g0 * 8);
    }
    __syncthreads();
#pragma unroll
    for (int kk = 0; kk < 2; ++kk) {
      half8 ah[2], bh[4];
#pragma unroll
      for (int t = 0; t < 2; ++t) {
        int ar = wm * 32 + t * 16 + l15;
        ah[t] = *(const half8*)&sA[ar * 64 + (((kk * 4 + quad) ^ (ar & 7)) * 8)];
      }
#pragma unroll
      for (int t = 0; t < 4; ++t) {
        int br = wn * 64 + t * 16 + l15;
        bh[t] = *(const half8*)&sB[br * 64 + (((kk * 4 + quad) ^ (br & 7)) * 8)];
      }
#pragma unroll
      for (int im = 0; im < 2; ++im)
#pragma unroll
        for (int in = 0; in < 4; ++in)
          acc[im][in] = mfma16(ah[im], bh[in], acc[im][in]);
    }
    __syncthreads();
  }
#pragma unroll
  for (int im = 0; im < 2; ++im)
#pragma unroll
    for (int in = 0; in < 4; ++in)
#pragma unroll
      for (int r = 0; r < 4; ++r) {
        int row = am0 + wm * 32 + im * 16 + quad * 4 + r;
        int col = bn0 + wn * 64 + in * 16 + l15;
        if (HALF_OUT)
          ((half_t*)Cv)[(size_t)row * 2048 + col] = (half_t)(acc[im][in][r] * scale);
        else
          ((float*)Cv)[(size_t)row * 2048 + col] = acc[im][in][r] * scale;
      }
}

// ---------------------------------------------------------------------------
// Flash attention, causal.  BM=BN=64, wave owns 16 q-rows.
// Grid 512 = 32 qtiles x 16 heads, complementary qt pairing (uniform 33
// k-iters per CU).  2 blocks/CU.  DPP softmax reductions.
__global__ __launch_bounds__(256, 2)
void k_flash(const half_t* __restrict__ Rh, const half_t* __restrict__ Rl,
             const half_t* __restrict__ VST, half_t* __restrict__ Ybig) {
  int idx = blockIdx.x;
  int h = idx & 15;
  int qt = (idx < 256) ? (31 - (idx >> 4)) : ((idx - 256) >> 4);
  int lane = threadIdx.x & 63, wave = threadIdx.x >> 6;
  int l15 = lane & 15, quad = lane >> 4;

  const half_t* RQh = Rh + (size_t)h * SEQ * 128;
  const half_t* RQl = Rl + (size_t)h * SEQ * 128;
  const half_t* RKh = Rh + (size_t)(NHEAD + h) * SEQ * 128;
  const half_t* RKl = Rl + (size_t)(NHEAD + h) * SEQ * 128;
  const half_t* Vt  = VST + (size_t)h * 128 * SEQ;  // [v][t]

  __shared__ __align__(16) half_t sKh[64 * 128];
  __shared__ __align__(16) half_t sKl[64 * 128];
  __shared__ __align__(16) half_t sVt[128 * 64];
  __shared__ __align__(16) half_t sP[64 * 72];

  int q0 = qt * 64;

  half8 qh[4], ql[4];
#pragma unroll
  for (int kk = 0; kk < 4; ++kk) {
    size_t ad = (size_t)(q0 + wave * 16 + l15) * 128 + kk * 32 + quad * 8;
    qh[kk] = *(const half8*)&RQh[ad];
    ql[kk] = *(const half8*)&RQl[ad];
  }

  float m_st[4], l_st[4];
  f32x4 oacc[8];
#pragma unroll
  for (int r = 0; r < 4; ++r) { m_st[r] = -INFINITY; l_st[r] = 0.0f; }
#pragma unroll
  for (int iv = 0; iv < 8; ++iv) oacc[iv] = (f32x4)0.0f;

  int nkb = qt + 1;
  for (int kb = 0; kb < nkb; ++kb) {
    int t0 = kb * 64;
#pragma unroll
    for (int i = 0; i < 4; ++i) {
      int c = wave * 4 + i;
      int rk = c * 4 + (lane >> 4);       // K row 0..63 (16 chunks/row)
      int ck = (lane & 15) ^ (rk & 15);
      gll16(RKh + (size_t)(t0 + rk) * 128 + ck * 8, sKh + c * 512);
      gll16(RKl + (size_t)(t0 + rk) * 128 + ck * 8, sKl + c * 512);
      int rv = c * 8 + (lane >> 3);       // V row 0..127 (8 chunks/row)
      int cv = (lane & 7) ^ (rv & 7);
      gll16(Vt + (size_t)rv * SEQ + t0 + cv * 8, sVt + c * 512);
    }
    __syncthreads();

    f32x4 sacc[4];
#pragma unroll
    for (int in = 0; in < 4; ++in) sacc[in] = (f32x4)0.0f;
#pragma unroll
    for (int kk = 0; kk < 4; ++kk)
#pragma unroll
      for (int in = 0; in < 4; ++in) {
        int bo = (in * 16 + l15) * 128 + (((kk * 4 + quad) ^ l15) * 8);
        half8 bh = *(const half8*)&sKh[bo];
        half8 bl = *(const half8*)&sKl[bo];
        sacc[in] = mfma16(qh[kk], bh, sacc[in]);
        sacc[in] = mfma16(qh[kk], bl, sacc[in]);
        sacc[in] = mfma16(ql[kk], bh, sacc[in]);
      }
    if (kb == qt) {  // diagonal block: mask t > s (local indices)
#pragma unroll
      for (int in = 0; in < 4; ++in)
#pragma unroll
        for (int r = 0; r < 4; ++r)
          if (in * 16 + l15 > wave * 16 + quad * 4 + r) sacc[in][r] = -1e30f;
    }
    float alpha[4];
#pragma unroll
    for (int r = 0; r < 4; ++r) {
      float mx = fmaxf(fmaxf(sacc[0][r], sacc[1][r]),
                       fmaxf(sacc[2][r], sacc[3][r]));
      mx = red16_max(mx);
      float mnew = fmaxf(m_st[r], mx);
      alpha[r] = __expf(m_st[r] - mnew);
      float sum = 0.0f;
#pragma unroll
      for (int in = 0; in < 4; ++in) {
        float p = __expf(sacc[in][r] - mnew);
        sacc[in][r] = p;
        sum += p;
      }
      sum = red16_sum(sum);
      l_st[r] = l_st[r] * alpha[r] + sum;
      m_st[r] = mnew;
    }
#pragma unroll
    for (int in = 0; in < 4; ++in)
#pragma unroll
      for (int r = 0; r < 4; ++r)
        sP[(wave * 16 + quad * 4 + r) * 72 + in * 16 + l15] =
            (half_t)sacc[in][r];
#pragma unroll
    for (int iv = 0; iv < 8; ++iv)
#pragma unroll
      for (int r = 0; r < 4; ++r) oacc[iv][r] *= alpha[r];

#pragma unroll
    for (int kk2 = 0; kk2 < 2; ++kk2) {
      half8 pa =
          *(const half8*)&sP[(wave * 16 + l15) * 72 + kk2 * 32 + quad * 8];
#pragma unroll
      for (int iv = 0; iv < 8; ++iv) {
        half8 vb = *(const half8*)&sVt[(iv * 16 + l15) * 64 +
                                       (((kk2 * 4 + quad) ^ (l15 & 7)) * 8)];
        oacc[iv] = mfma16(pa, vb, oacc[iv]);
      }
    }
    __syncthreads();
  }
  float invl[4];
#pragma unroll
  for (int r = 0; r < 4; ++r) invl[r] = 1.0f / l_st[r];
#pragma unroll
  for (int iv = 0; iv < 8; ++iv)
#pragma unroll
    for (int r = 0; r < 4; ++r) {
      int row = q0 + wave * 16 + quad * 4 + r;
      int col = h * 128 + iv * 16 + l15;
      Ybig[(size_t)row * 2048 + col] = (half_t)(oacc[iv][r] * invl[r]);
    }
}

// ---------------------------------------------------------------------------
extern "C" void kernel_launch(void* const* d_in, const int* in_sizes, int n_in,
                              void* d_out, int out_size, void* d_ws,
                              size_t ws_size, hipStream_t stream) {
  const float* x = (const float*)d_in[0];
  const float* q = (const float*)d_in[1];
  const float* k = (const float*)d_in[2];
  const float* v = (const float*)d_in[3];
  const float* o = (const float*)d_in[4];
  const float* theta = (const float*)d_in[5];
  float* out = (float*)d_out;

  char* ws = (char*)d_ws;
  const size_t HB = (size_t)2048 * 2048 * 2;  // 8 MiB
  half_t* Xh   = (half_t*)(ws);            // [2048 s][2048 d]
  half_t* Xl   = (half_t*)(ws + HB);
  half_t* WTh  = (half_t*)(ws + 2 * HB);   // [2][16][128 e][2048 d] (2 HB)
  half_t* WTl  = (half_t*)(ws + 4 * HB);   // (2 HB)
  half_t* VhT  = (half_t*)(ws + 6 * HB);   // [16][128 v][2048 d]
  half_t* OT   = (half_t*)(ws + 7 * HB);   // [2048 d][2048 hv]
  half_t* Rh   = (half_t*)(ws + 8 * HB);   // [2][16][2048 s][128 e] (2 HB)
  half_t* Rl   = (half_t*)(ws + 10 * HB);  // (2 HB)
  float2* trig = (float2*)(ws + 12 * HB);  // [2048 s][64 e] = 1 MB
  half_t* VST  = (half_t*)(ws + 2 * HB);   // overlay WTh (dead after proj)
  half_t* Ybig = (half_t*)(ws + 3 * HB);   // overlay WTh upper half

  // 1. preprocessing: split, 4 transposes, trig table (one launch)
  k_pre<<<20992, 256, 0, stream>>>(x, q, k, v, o, theta, Xh, Xl, WTh, WTl,
                                   VhT, OT, trig);
  // 2. q/k projections + fused rope -> Rh/Rl
  k_proj<<<dim3(16, 32), 256, 0, stream>>>(Xh, Xl, WTh, WTl, trig, Rh, Rl);
  // 3. v projection -> VS^T [h][v][t] fp16
  k_gemm1<1><<<dim3(16, 32), 256, 0, stream>>>(VhT, Xh, VST, 1.0f);
  // 4. flash attention -> Ybig [s][h*128+v] fp16
  k_flash<<<512, 256, 0, stream>>>(Rh, Rl, VST, Ybig);
  // 5. out projection: z = Ybig @ OT * (1/2048) -> fp32
  k_gemm1<0><<<dim3(16, 32), 256, 0, stream>>>(Ybig, OT, out, 1.0f / 2048.0f);
}